// Round 11
// baseline (617.257 us; speedup 1.0000x reference)
//
#include <hip/hip_runtime.h>
#include <hip/hip_bf16.h>
#include <math.h>

#define N_NODES 50000
#define N_EDGES 1600000
#define N_TOT   (N_EDGES + N_NODES)

typedef unsigned short ushort_t;
typedef short short8v __attribute__((ext_vector_type(8)));
typedef float f32x4 __attribute__((ext_vector_type(4)));

__device__ __forceinline__ float lrelu(float x) { return x > 0.f ? x : 0.2f * x; }
__device__ __forceinline__ float bf2f(ushort_t u) { return __uint_as_float((unsigned)u << 16); }
__device__ __forceinline__ ushort_t f2bf(float f) {
    union { __hip_bfloat16 b; ushort_t u; } cv;
    cv.b = __float2bfloat16(f);
    return cv.u;
}

// ---------------- CSR build ----------------
__global__ void k_count(const int* __restrict__ ei, int* __restrict__ cnt) {
    int e = blockIdx.x * 256 + threadIdx.x;
    if (e >= N_TOT) return;
    int dst = (e < N_EDGES) ? ei[N_EDGES + e] : (e - N_EDGES);
    atomicAdd(&cnt[dst], 1);
}

__global__ void k_scan1(const int* __restrict__ cnt, int* __restrict__ bsum) {
    __shared__ int ws[4];
    int g = blockIdx.x * 256 + threadIdx.x;
    int lane = threadIdx.x & 63, wv = threadIdx.x >> 6;
    int x = (g < N_NODES) ? cnt[g] : 0;
#pragma unroll
    for (int s = 1; s < 64; s <<= 1) x += __shfl_xor(x, s, 64);
    if (lane == 0) ws[wv] = x;
    __syncthreads();
    if (threadIdx.x == 0) bsum[blockIdx.x] = ws[0] + ws[1] + ws[2] + ws[3];
}

__global__ void k_scan2(const int* __restrict__ bsum, int* __restrict__ boff) {
    __shared__ int ws[4];
    const int NB = (N_NODES + 255) / 256;
    int t = threadIdx.x, lane = t & 63, wv = t >> 6;
    int v = (t < NB) ? bsum[t] : 0;
    int x = v;
#pragma unroll
    for (int s = 1; s < 64; s <<= 1) { int tt = __shfl_up(x, s, 64); if (lane >= s) x += tt; }
    if (lane == 63) ws[wv] = x;
    __syncthreads();
    int add = 0;
#pragma unroll
    for (int w = 0; w < 4; ++w) add += (w < wv) ? ws[w] : 0;
    x += add;
    if (t < NB) boff[t] = x - v;   // exclusive
}

__global__ void k_scan3(const int* __restrict__ cnt, const int* __restrict__ boff,
                        int* __restrict__ off) {
    __shared__ int ws[4];
    int g = blockIdx.x * 256 + threadIdx.x;
    int lane = threadIdx.x & 63, wv = threadIdx.x >> 6;
    int v = (g < N_NODES) ? cnt[g] : 0;
    int x = v;
#pragma unroll
    for (int s = 1; s < 64; s <<= 1) { int tt = __shfl_up(x, s, 64); if (lane >= s) x += tt; }
    if (lane == 63) ws[wv] = x;
    __syncthreads();
    int add = 0;
#pragma unroll
    for (int w = 0; w < 4; ++w) add += (w < wv) ? ws[w] : 0;
    x += add;
    if (g < N_NODES) off[g + 1] = boff[blockIdx.x] + x;
    if (g == 0) off[0] = 0;
}

// self-loop records: {n, aloop packed}
__global__ void k_fill_loop(const int* __restrict__ off, int* __restrict__ cur,
                            const float* __restrict__ aloop, int4* __restrict__ rec) {
    int n = blockIdx.x * 256 + threadIdx.x;
    if (n >= N_NODES) return;
    unsigned ax = (unsigned)f2bf(aloop[0]) | ((unsigned)f2bf(aloop[1]) << 16);
    unsigned ay = (unsigned)f2bf(aloop[2]) | ((unsigned)f2bf(aloop[3]) << 16);
    int pos = off[n] + atomicAdd(&cur[n], 1);
    rec[pos] = make_int4(n, (int)ax, (int)ay, 0);
}

__global__ void k_extract(const int4* __restrict__ rec, int* __restrict__ csrc) {
    int p = blockIdx.x * 256 + threadIdx.x;
    if (p < N_TOT) csrc[p] = rec[p].x;
}

// ---------------- edge attention precompute ----------------
__global__ void k_v(const float* __restrict__ We0, const float* __restrict__ ae0,
                    float* __restrict__ v) {
    int t = threadIdx.x;            // 0..127
    int h = t >> 5, k = t & 31;
    float s = 0.f;
    for (int c = 0; c < 32; ++c) s += We0[k * 128 + h * 32 + c] * ae0[h * 32 + c];
    v[h * 32 + k] = s;
}

// epW (32x32 row-major) -> bf16 MFMA fragments (used as A = epW^T tiles)
__global__ void k_wepbf(const float* __restrict__ epW, ushort_t* __restrict__ Bp) {
    int t = threadIdx.x;              // 0..127
    if (t >= 128) return;
    int lane = t & 63, ct = t >> 6;
    int j = ct * 16 + (lane & 15);
    int kbase = (lane >> 4) * 8;
    ushort_t o[8];
#pragma unroll
    for (int jj = 0; jj < 8; ++jj) o[jj] = f2bf(epW[(kbase + jj) * 32 + j]);
    ((uint4*)Bp)[t] = *(uint4*)o;
}

// MFMA edge-attention (transposed) + fused CSR scatter; atomic hoisted to hide latency.
__global__ void k_alpha_mfma(const float* __restrict__ eattr, const ushort_t* __restrict__ Aw,
                             const float* __restrict__ epb, const float* __restrict__ v,
                             const int* __restrict__ ei, const int* __restrict__ off,
                             int* __restrict__ cur, int4* __restrict__ rec,
                             float* __restrict__ easum) {
    __shared__ float sums[4][32];
    int tid = threadIdx.x;
    int lane = tid & 63, wv = tid >> 6;
    int c = lane & 15, g = lane >> 4;   // c = edge column, g = channel group
    int e0base = blockIdx.x * 256 + wv * 64;

    // ---- hoisted: CSR slot reservation (latency hides under MFMA pipeline below) ----
    int e = e0base + lane;
    int src = ei[e], dst = ei[N_EDGES + e];
    int pos = off[dst] + atomicAdd(&cur[dst], 1);

    // ---- hoisted: stage all eattr tiles (8 x float4 in flight) ----
    float4 F0[4], F1[4];
#pragma unroll
    for (int t = 0; t < 4; ++t) {
        const float4* ap = (const float4*)(eattr + (size_t)(e0base + t * 16 + c) * 32 + g * 8);
        F0[t] = ap[0];
        F1[t] = ap[1];
    }

    short8v a0 = ((const short8v*)Aw)[lane];        // channels 0-15
    short8v a1 = ((const short8v*)Aw)[64 + lane];   // channels 16-31

    float eb0[4], eb1[4], vv0[4][4], vv1[4][4];
#pragma unroll
    for (int r = 0; r < 4; ++r) {
        eb0[r] = epb[g * 4 + r];
        eb1[r] = epb[16 + g * 4 + r];
#pragma unroll
        for (int h = 0; h < 4; ++h) {
            vv0[h][r] = v[h * 32 + g * 4 + r];
            vv1[h][r] = v[h * 32 + 16 + g * 4 + r];
        }
    }

    float se0[4] = {0.f, 0.f, 0.f, 0.f}, se1[4] = {0.f, 0.f, 0.f, 0.f};
    uint2 oo0, oo1, oo2, oo3;
#pragma unroll
    for (int t = 0; t < 4; ++t) {
        float4 f0 = F0[t], f1 = F1[t];
        ushort_t ai[8];
        ai[0] = f2bf(f0.x); ai[1] = f2bf(f0.y); ai[2] = f2bf(f0.z); ai[3] = f2bf(f0.w);
        ai[4] = f2bf(f1.x); ai[5] = f2bf(f1.y); ai[6] = f2bf(f1.z); ai[7] = f2bf(f1.w);
        short8v b = *(short8v*)ai;                  // B = eattr^T fragment
        f32x4 acc0 = (f32x4){0.f, 0.f, 0.f, 0.f};
        f32x4 acc1 = (f32x4){0.f, 0.f, 0.f, 0.f};
        acc0 = __builtin_amdgcn_mfma_f32_16x16x32_bf16(a0, b, acc0, 0, 0, 0);
        acc1 = __builtin_amdgcn_mfma_f32_16x16x32_bf16(a1, b, acc1, 0, 0, 0);
        float p0 = 0.f, p1 = 0.f, p2 = 0.f, p3 = 0.f;
#pragma unroll
        for (int r = 0; r < 4; ++r) {
            float u0 = fmaxf(acc0[r] + eb0[r], 0.f);
            float u1 = fmaxf(acc1[r] + eb1[r], 0.f);
            se0[r] += u0; se1[r] += u1;
            p0 += u0 * vv0[0][r] + u1 * vv1[0][r];
            p1 += u0 * vv0[1][r] + u1 * vv1[1][r];
            p2 += u0 * vv0[2][r] + u1 * vv1[2][r];
            p3 += u0 * vv0[3][r] + u1 * vv1[3][r];
        }
        // butterfly over lane bits 4,5: EVERY lane ends with the full dot for its c
        p0 += __shfl_xor(p0, 16, 64); p0 += __shfl_xor(p0, 32, 64);
        p1 += __shfl_xor(p1, 16, 64); p1 += __shfl_xor(p1, 32, 64);
        p2 += __shfl_xor(p2, 16, 64); p2 += __shfl_xor(p2, 32, 64);
        p3 += __shfl_xor(p3, 16, 64); p3 += __shfl_xor(p3, 32, 64);
        uint2 o;
        o.x = (unsigned)f2bf(p0) | ((unsigned)f2bf(p1) << 16);
        o.y = (unsigned)f2bf(p2) | ((unsigned)f2bf(p3) << 16);
        if (t == 0) oo0 = o; else if (t == 1) oo1 = o; else if (t == 2) oo2 = o; else oo3 = o;
    }
    // lane handles edge e0base + lane  (tile t = g, column c)
    uint2 o = oo0;
    o.x = (g == 1) ? oo1.x : o.x; o.y = (g == 1) ? oo1.y : o.y;
    o.x = (g == 2) ? oo2.x : o.x; o.y = (g == 2) ? oo2.y : o.y;
    o.x = (g == 3) ? oo3.x : o.x; o.y = (g == 3) ? oo3.y : o.y;
    rec[pos] = make_int4(src, (int)o.x, (int)o.y, 0);

    // easum
#pragma unroll
    for (int r = 0; r < 4; ++r) {
#pragma unroll
        for (int m = 1; m < 16; m <<= 1) {
            se0[r] += __shfl_xor(se0[r], m, 64);
            se1[r] += __shfl_xor(se1[r], m, 64);
        }
    }
    if (c == 0) {
#pragma unroll
        for (int r = 0; r < 4; ++r) {
            sums[wv][g * 4 + r] = se0[r];
            sums[wv][16 + g * 4 + r] = se1[r];
        }
    }
    __syncthreads();
    if (tid < 32) {
        atomicAdd(&easum[tid], sums[0][tid] + sums[1][tid] + sums[2][tid] + sums[3][tid]);
    }
}

__global__ void k_aloop(const float* __restrict__ easum, const float* __restrict__ v,
                        float* __restrict__ aloop) {
    int h = threadIdx.x;
    if (h >= 4) return;
    float s = 0.f;
    for (int c = 0; c < 32; ++c) s += (easum[c] * (1.f / (float)N_EDGES)) * v[h * 32 + c];
    aloop[h] = s;
}

// ---------------- weight conversion: 128x128 f32 -> MFMA B-fragment bf16 ----------------
__global__ void k_wbf(const float* __restrict__ W, ushort_t* __restrict__ Bp) {
    int t = blockIdx.x * 256 + threadIdx.x;   // 0..2047
    if (t >= 2048) return;
    int lane = t & 63;
    int ct = (t >> 6) & 7;
    int kb = t >> 9;
    int j = ct * 16 + (lane & 15);
    int kbase = kb * 32 + (lane >> 4) * 8;
    ushort_t o[8];
#pragma unroll
    for (int jj = 0; jj < 8; ++jj) o[jj] = f2bf(W[(kbase + jj) * 128 + j]);
    ((uint4*)Bp)[t] = *(uint4*)o;
}

// W2 (512x128 effective) -> B-fragments
__global__ void k_w2bf(const float* __restrict__ W2, ushort_t* __restrict__ Bp) {
    int t = blockIdx.x * 256 + threadIdx.x;   // 0..8191
    if (t >= 8192) return;
    int lane = t & 63;
    int ct = (t >> 6) & 7;
    int kb = t >> 9;
    int j = ct * 16 + (lane & 15);
    int kbase = kb * 32 + (lane >> 4) * 8;
    ushort_t o[8];
#pragma unroll
    for (int jj = 0; jj < 8; ++jj) {
        int kk = kbase + jj;
        int h = kk >> 7, kp = kk & 127;
        o[jj] = f2bf(W2[kp * 512 + h * 128 + j]);
    }
    ((uint4*)Bp)[t] = *(uint4*)o;
}

// ---------------- GEMMs ----------------
__global__ void k_proj_in(const float* __restrict__ x, const float* __restrict__ W,
                          const float* __restrict__ b, float* __restrict__ h,
                          ushort_t* __restrict__ h16) {
    int j = threadIdx.x;               // 0..127
    int n0 = blockIdx.x * 4;
    const float* x0 = x + (size_t)n0 * 64;
    float a0 = 0.f, a1 = 0.f, a2 = 0.f, a3 = 0.f;
    for (int k = 0; k < 64; ++k) {
        float w = W[k * 128 + j];
        a0 += x0[k] * w;
        a1 += x0[64 + k] * w;
        a2 += x0[128 + k] * w;
        a3 += x0[192 + k] * w;
    }
    float bb = b[j];
    a0 = fmaxf(a0 + bb, 0.f); a1 = fmaxf(a1 + bb, 0.f);
    a2 = fmaxf(a2 + bb, 0.f); a3 = fmaxf(a3 + bb, 0.f);
    h[(size_t)(n0 + 0) * 128 + j] = a0;
    h[(size_t)(n0 + 1) * 128 + j] = a1;
    h[(size_t)(n0 + 2) * 128 + j] = a2;
    h[(size_t)(n0 + 3) * 128 + j] = a3;
    h16[(size_t)(n0 + 0) * 128 + j] = f2bf(a0);
    h16[(size_t)(n0 + 1) * 128 + j] = f2bf(a1);
    h16[(size_t)(n0 + 2) * 128 + j] = f2bf(a2);
    h16[(size_t)(n0 + 3) * 128 + j] = f2bf(a3);
}

// MFMA projection: hp16 = bf16(h16 @ Wbf); fused ls/ld
__global__ void k_proj_attn_mfma(const ushort_t* __restrict__ h16, const ushort_t* __restrict__ Bp,
                                 const float* __restrict__ as_, const float* __restrict__ ad_,
                                 ushort_t* __restrict__ hp16, float* __restrict__ ls,
                                 float* __restrict__ ld) {
    int tid = threadIdx.x;
    int lane = tid & 63, wid = tid >> 6;
    int n0 = blockIdx.x * 64 + wid * 16;
    int arow = n0 + (lane & 15);
    int arc = arow < N_NODES ? arow : 0;
    int koff = (lane >> 4) * 8;
    const short8v* ap = (const short8v*)(h16 + (size_t)arc * 128 + koff);
    const short8v* bp = (const short8v*)Bp;

    f32x4 acc[8];
#pragma unroll
    for (int ct = 0; ct < 8; ++ct) acc[ct] = (f32x4){0.f, 0.f, 0.f, 0.f};
#pragma unroll
    for (int kb = 0; kb < 4; ++kb) {
        short8v a = ap[kb * 4];
#pragma unroll
        for (int ct = 0; ct < 8; ++ct) {
            short8v b = bp[(kb * 8 + ct) * 64 + lane];
            acc[ct] = __builtin_amdgcn_mfma_f32_16x16x32_bf16(a, b, acc[ct], 0, 0, 0);
        }
    }

    int q = lane >> 4, c = lane & 15;
#pragma unroll
    for (int reg = 0; reg < 4; ++reg) {
        int row = n0 + q * 4 + reg;
        if (row < N_NODES) {
#pragma unroll
            for (int ct = 0; ct < 8; ++ct)
                hp16[(size_t)row * 128 + ct * 16 + c] = f2bf(acc[ct][reg]);
        }
    }
#pragma unroll
    for (int h = 0; h < 4; ++h) {
        float alo = as_[h * 32 + c], ahi = as_[h * 32 + 16 + c];
        float dlo = ad_[h * 32 + c], dhi = ad_[h * 32 + 16 + c];
#pragma unroll
        for (int reg = 0; reg < 4; ++reg) {
            float s = acc[2 * h][reg] * alo + acc[2 * h + 1][reg] * ahi;
            float d = acc[2 * h][reg] * dlo + acc[2 * h + 1][reg] * dhi;
#pragma unroll
            for (int m = 1; m < 16; m <<= 1) {
                s += __shfl_xor(s, m, 64);
                d += __shfl_xor(d, m, 64);
            }
            int row = n0 + q * 4 + reg;
            if (c == 0 && row < N_NODES) {
                ls[row * 4 + h] = s;
                ld[row * 4 + h] = d;
            }
        }
    }
}

// u_s[h,k] = sum_c W2[k, h*128+c] * as2[h,c] (and u_d)
__global__ void k_u(const float* __restrict__ W2, const float* __restrict__ as2,
                    const float* __restrict__ ad2, float* __restrict__ us,
                    float* __restrict__ ud) {
    int t = blockIdx.x * 256 + threadIdx.x;
    if (t >= 512) return;
    int h = t >> 7, k = t & 127;
    float ss = 0.f, dd = 0.f;
    for (int c = 0; c < 128; ++c) {
        float w = W2[k * 512 + h * 128 + c];
        ss += w * as2[h * 128 + c];
        dd += w * ad2[h * 128 + c];
    }
    us[h * 128 + k] = ss;
    ud[h * 128 + k] = dd;
}

// ---- GAT aggregation + fused residual/LayerNorm (+ optional ls2/ld2), 4 nodes/block --
template <bool L0>
__global__ void k_agg32(const int* __restrict__ off, const int4* __restrict__ rec,
                        const int* __restrict__ csrc,
                        const ushort_t* __restrict__ hp16, const float* __restrict__ ls,
                        const float* __restrict__ ld,
                        const float* __restrict__ bias, const float* __restrict__ g,
                        const float* __restrict__ be,
                        float* h, ushort_t* __restrict__ h16,
                        const float* __restrict__ us, const float* __restrict__ ud,
                        float* __restrict__ ls2, float* __restrict__ ld2) {
    __shared__ float swt[4][64][4];
    __shared__ int ssrc[4][64];
    int wv = threadIdx.x >> 6, lane = threadIdx.x & 63;
    int n = blockIdx.x * 4 + wv;
    int beg = off[n], deg = off[n + 1] - beg;
    float4 ldv = *(const float4*)(ld + n * 4);

    int hsel = lane >> 4;   // head of channels {2*lane, 2*lane+1}
    float acc0 = 0.f, acc1 = 0.f;
    float d0 = 0.f, d1 = 0.f, d2 = 0.f, d3 = 0.f;
    for (int base = 0; base < deg; base += 64) {
        int i = base + lane;
        float w0 = 0, w1 = 0, w2 = 0, w3 = 0;
        int s = 0;
        if (i < deg) {
            float a0 = 0, a1 = 0, a2 = 0, a3 = 0;
            if (L0) {
                int4 r = rec[beg + i];
                s = r.x;
                a0 = bf2f((ushort_t)((unsigned)r.y & 0xffffu));
                a1 = bf2f((ushort_t)((unsigned)r.y >> 16));
                a2 = bf2f((ushort_t)((unsigned)r.z & 0xffffu));
                a3 = bf2f((ushort_t)((unsigned)r.z >> 16));
            } else {
                s = csrc[beg + i];
            }
            float4 lsv = *(const float4*)(ls + s * 4);
            w0 = __expf(lrelu(lsv.x + ldv.x + a0)); d0 += w0;
            w1 = __expf(lrelu(lsv.y + ldv.y + a1)); d1 += w1;
            w2 = __expf(lrelu(lsv.z + ldv.z + a2)); d2 += w2;
            w3 = __expf(lrelu(lsv.w + ldv.w + a3)); d3 += w3;
        }
        *(float4*)&swt[wv][lane][0] = make_float4(w0, w1, w2, w3);
        ssrc[wv][lane] = s;
        int cnt = min(64, deg - base);
        int jj = 0;
        for (; jj + 4 <= cnt; jj += 4) {
            float wA = swt[wv][jj + 0][hsel]; int sA = ssrc[wv][jj + 0];
            float wB = swt[wv][jj + 1][hsel]; int sB = ssrc[wv][jj + 1];
            float wC = swt[wv][jj + 2][hsel]; int sC = ssrc[wv][jj + 2];
            float wD = swt[wv][jj + 3][hsel]; int sD = ssrc[wv][jj + 3];
            ushort2 vA = ((const ushort2*)(hp16 + (size_t)sA * 128))[lane];
            ushort2 vB = ((const ushort2*)(hp16 + (size_t)sB * 128))[lane];
            ushort2 vC = ((const ushort2*)(hp16 + (size_t)sC * 128))[lane];
            ushort2 vD = ((const ushort2*)(hp16 + (size_t)sD * 128))[lane];
            acc0 += bf2f(vA.x) * wA; acc1 += bf2f(vA.y) * wA;
            acc0 += bf2f(vB.x) * wB; acc1 += bf2f(vB.y) * wB;
            acc0 += bf2f(vC.x) * wC; acc1 += bf2f(vC.y) * wC;
            acc0 += bf2f(vD.x) * wD; acc1 += bf2f(vD.y) * wD;
        }
        for (; jj < cnt; ++jj) {
            float wA = swt[wv][jj][hsel];
            int sA = ssrc[wv][jj];
            ushort2 vA = ((const ushort2*)(hp16 + (size_t)sA * 128))[lane];
            acc0 += bf2f(vA.x) * wA;
            acc1 += bf2f(vA.y) * wA;
        }
    }
#pragma unroll
    for (int k = 1; k < 64; k <<= 1) {
        d0 += __shfl_xor(d0, k, 64); d1 += __shfl_xor(d1, k, 64);
        d2 += __shfl_xor(d2, k, 64); d3 += __shfl_xor(d3, k, 64);
    }
    float dsel = (hsel == 0) ? d0 : (hsel == 1) ? d1 : (hsel == 2) ? d2 : d3;
    float2 bb = ((const float2*)bias)[lane];
    size_t hbase = (size_t)n * 128;
    float2 hres = ((const float2*)(h + hbase))[lane];
    float v0 = acc0 / dsel + bb.x + hres.x;
    float v1 = acc1 / dsel + bb.y + hres.y;
    float s = v0 + v1, ss = v0 * v0 + v1 * v1;
#pragma unroll
    for (int k = 1; k < 64; k <<= 1) { s += __shfl_xor(s, k, 64); ss += __shfl_xor(ss, k, 64); }
    float mean = s * (1.f / 128.f);
    float var = ss * (1.f / 128.f) - mean * mean;
    float inv = rsqrtf(var + 1e-5f);
    float2 gg = ((const float2*)g)[lane];
    float2 bee = ((const float2*)be)[lane];
    float r0 = (v0 - mean) * inv * gg.x + bee.x;
    float r1 = (v1 - mean) * inv * gg.y + bee.y;
    ((float2*)(h + hbase))[lane] = make_float2(r0, r1);
    ushort2 o16; o16.x = f2bf(r0); o16.y = f2bf(r1);
    ((ushort2*)(h16 + hbase))[lane] = o16;

    if (!L0) {
        // fused layer-2 attention dots: ls2/ld2 = h . us/ud per head
        float sh[4], dh[4];
#pragma unroll
        for (int hh = 0; hh < 4; ++hh) {
            float2 u2 = ((const float2*)(us + hh * 128))[lane];
            float2 w2 = ((const float2*)(ud + hh * 128))[lane];
            sh[hh] = r0 * u2.x + r1 * u2.y;
            dh[hh] = r0 * w2.x + r1 * w2.y;
        }
#pragma unroll
        for (int k = 1; k < 64; k <<= 1) {
#pragma unroll
            for (int hh = 0; hh < 4; ++hh) {
                sh[hh] += __shfl_xor(sh[hh], k, 64);
                dh[hh] += __shfl_xor(dh[hh], k, 64);
            }
        }
        if (lane == 0) {
#pragma unroll
            for (int hh = 0; hh < 4; ++hh) {
                ls2[n * 4 + hh] = sh[hh];
                ld2[n * 4 + hh] = dh[hh];
            }
        }
    }
}

// ---------- layer-2 aggregation: single-pass, gather INPUT h (bf16), 4 nodes/block --
__global__ void k_agg2(const int* __restrict__ off, const int* __restrict__ csrc,
                       const ushort_t* __restrict__ h16, const float* __restrict__ ls,
                       const float* __restrict__ ld, ushort_t* __restrict__ aggq) {
    __shared__ float4 swt[4][64];
    __shared__ int ssrc[4][64];
    int wv = threadIdx.x >> 6, lane = threadIdx.x & 63;
    int n = blockIdx.x * 4 + wv;
    int beg = off[n], deg = off[n + 1] - beg;
    float4 ldv = *(const float4*)(ld + n * 4);

    float a00 = 0, a01 = 0, a10 = 0, a11 = 0, a20 = 0, a21 = 0, a30 = 0, a31 = 0;
    float d0 = 0, d1 = 0, d2 = 0, d3 = 0;
    for (int base = 0; base < deg; base += 64) {
        int i = base + lane;
        float w0 = 0, w1 = 0, w2 = 0, w3 = 0;
        int s = 0;
        if (i < deg) {
            s = csrc[beg + i];
            float4 lsv = *(const float4*)(ls + s * 4);
            w0 = __expf(lrelu(lsv.x + ldv.x)); d0 += w0;
            w1 = __expf(lrelu(lsv.y + ldv.y)); d1 += w1;
            w2 = __expf(lrelu(lsv.z + ldv.z)); d2 += w2;
            w3 = __expf(lrelu(lsv.w + ldv.w)); d3 += w3;
        }
        swt[wv][lane] = make_float4(w0, w1, w2, w3);
        ssrc[wv][lane] = s;
        int cnt = min(64, deg - base);
        int jj = 0;
        for (; jj + 2 <= cnt; jj += 2) {
            float4 wA = swt[wv][jj];     int sA = ssrc[wv][jj];
            float4 wB = swt[wv][jj + 1]; int sB = ssrc[wv][jj + 1];
            ushort2 vA = ((const ushort2*)(h16 + (size_t)sA * 128))[lane];
            ushort2 vB = ((const ushort2*)(h16 + (size_t)sB * 128))[lane];
            float fA0 = bf2f(vA.x), fA1 = bf2f(vA.y);
            float fB0 = bf2f(vB.x), fB1 = bf2f(vB.y);
            a00 += fA0 * wA.x; a01 += fA1 * wA.x;
            a10 += fA0 * wA.y; a11 += fA1 * wA.y;
            a20 += fA0 * wA.z; a21 += fA1 * wA.z;
            a30 += fA0 * wA.w; a31 += fA1 * wA.w;
            a00 += fB0 * wB.x; a01 += fB1 * wB.x;
            a10 += fB0 * wB.y; a11 += fB1 * wB.y;
            a20 += fB0 * wB.z; a21 += fB1 * wB.z;
            a30 += fB0 * wB.w; a31 += fB1 * wB.w;
        }
        for (; jj < cnt; ++jj) {
            float4 w4 = swt[wv][jj];
            int sj = ssrc[wv][jj];
            ushort2 v = ((const ushort2*)(h16 + (size_t)sj * 128))[lane];
            float f0 = bf2f(v.x), f1 = bf2f(v.y);
            a00 += f0 * w4.x; a01 += f1 * w4.x;
            a10 += f0 * w4.y; a11 += f1 * w4.y;
            a20 += f0 * w4.z; a21 += f1 * w4.z;
            a30 += f0 * w4.w; a31 += f1 * w4.w;
        }
    }
#pragma unroll
    for (int k = 1; k < 64; k <<= 1) {
        d0 += __shfl_xor(d0, k, 64); d1 += __shfl_xor(d1, k, 64);
        d2 += __shfl_xor(d2, k, 64); d3 += __shfl_xor(d3, k, 64);
    }
    float r0 = 0.25f / d0, r1 = 0.25f / d1, r2 = 0.25f / d2, r3 = 0.25f / d3;
    ushort_t* base_p = aggq + (size_t)n * 512;
    ushort2 w;
    w.x = f2bf(a00 * r0); w.y = f2bf(a01 * r0); ((ushort2*)(base_p      ))[lane] = w;
    w.x = f2bf(a10 * r1); w.y = f2bf(a11 * r1); ((ushort2*)(base_p + 128))[lane] = w;
    w.x = f2bf(a20 * r2); w.y = f2bf(a21 * r2); ((ushort2*)(base_p + 256))[lane] = w;
    w.x = f2bf(a30 * r3); w.y = f2bf(a31 * r3); ((ushort2*)(base_p + 384))[lane] = w;
}

// --- MFMA GEMM: t = LN(aggq @ W2bf + bias2 + hbuf); out = t @ W_out + b_out (fused) ---
__global__ void k_gemm_post(const ushort_t* __restrict__ aggq, const ushort_t* __restrict__ Bp,
                            const float* __restrict__ bias, const float* __restrict__ g,
                            const float* __restrict__ be, const float* __restrict__ hbuf,
                            const ushort_t* __restrict__ Wout_bp, const float* __restrict__ b_out,
                            float* __restrict__ out) {
    __shared__ ushort_t tile[4][16][136];   // per-wave 16x128 bf16, padded (272B rows)
    int tid = threadIdx.x;
    int lane = tid & 63, wid = tid >> 6;
    int n0 = blockIdx.x * 64 + wid * 16;
    int arow = n0 + (lane & 15);
    int arc = arow < N_NODES ? arow : 0;
    int koff = (lane >> 4) * 8;

    const short8v* ap = (const short8v*)(aggq + (size_t)arc * 512 + koff);
    const short8v* bp = (const short8v*)Bp;

    f32x4 acc[8];
#pragma unroll
    for (int ct = 0; ct < 8; ++ct) acc[ct] = (f32x4){0.f, 0.f, 0.f, 0.f};
#pragma unroll
    for (int kb = 0; kb < 16; ++kb) {
        short8v a = ap[kb * 4];
#pragma unroll
        for (int ct = 0; ct < 8; ++ct) {
            short8v b = bp[(kb * 8 + ct) * 64 + lane];
            acc[ct] = __builtin_amdgcn_mfma_f32_16x16x32_bf16(a, b, acc[ct], 0, 0, 0);
        }
    }

    int q = lane >> 4, c = lane & 15;
    float gv[8], bev[8], bv[8];
#pragma unroll
    for (int ct = 0; ct < 8; ++ct) {
        int col = ct * 16 + c;
        gv[ct] = g[col]; bev[ct] = be[col]; bv[ct] = bias[col];
    }
#pragma unroll
    for (int reg = 0; reg < 4; ++reg) {
        int row = n0 + q * 4 + reg;
        int rc = row < N_NODES ? row : 0;
        float v[8];
        float s = 0.f, ss = 0.f;
#pragma unroll
        for (int ct = 0; ct < 8; ++ct) {
            float val = acc[ct][reg] + bv[ct] + hbuf[(size_t)rc * 128 + ct * 16 + c];
            v[ct] = val; s += val; ss += val * val;
        }
#pragma unroll
        for (int m = 1; m < 16; m <<= 1) {
            s += __shfl_xor(s, m, 64);
            ss += __shfl_xor(ss, m, 64);
        }
        float mean = s * (1.f / 128.f);
        float var = ss * (1.f / 128.f) - mean * mean;
        float inv = rsqrtf(var + 1e-5f);
        int lrow = q * 4 + reg;
#pragma unroll
        for (int ct = 0; ct < 8; ++ct)
            tile[wid][lrow][ct * 16 + c] = f2bf((v[ct] - mean) * inv * gv[ct] + bev[ct]);
    }

    // second GEMM: out = tile @ W_out + b_out (wave-private tile; same-wave DS ordering)
    const short8v* wp = (const short8v*)Wout_bp;
    f32x4 acc2[8];
#pragma unroll
    for (int ct = 0; ct < 8; ++ct) acc2[ct] = (f32x4){0.f, 0.f, 0.f, 0.f};
#pragma unroll
    for (int kb = 0; kb < 4; ++kb) {
        short8v a = *(const short8v*)&tile[wid][lane & 15][kb * 32 + koff];
#pragma unroll
        for (int ct = 0; ct < 8; ++ct) {
            short8v b = wp[(kb * 8 + ct) * 64 + lane];
            acc2[ct] = __builtin_amdgcn_mfma_f32_16x16x32_bf16(a, b, acc2[ct], 0, 0, 0);
        }
    }
    float bo[8];
#pragma unroll
    for (int ct = 0; ct < 8; ++ct) bo[ct] = b_out[ct * 16 + c];
#pragma unroll
    for (int reg = 0; reg < 4; ++reg) {
        int row = n0 + q * 4 + reg;
        if (row < N_NODES) {
#pragma unroll
            for (int ct = 0; ct < 8; ++ct)
                out[(size_t)row * 128 + ct * 16 + c] = acc2[ct][reg] + bo[ct];
        }
    }
}

extern "C" void kernel_launch(void* const* d_in, const int* in_sizes, int n_in,
                              void* d_out, int out_size, void* d_ws, size_t ws_size,
                              hipStream_t stream) {
    const float* x     = (const float*)d_in[0];
    const int*   ei    = (const int*)d_in[1];
    const float* eattr = (const float*)d_in[2];
    const float* W_in  = (const float*)d_in[3];
    const float* b_in  = (const float*)d_in[4];
    const float* epW   = (const float*)d_in[5];
    const float* epb   = (const float*)d_in[6];
    const float* W0    = (const float*)d_in[7];
    const float* as0   = (const float*)d_in[8];
    const float* ad0   = (const float*)d_in[9];
    const float* We0   = (const float*)d_in[10];
    const float* ae0   = (const float*)d_in[11];
    const float* bias0 = (const float*)d_in[12];
    const float* g0    = (const float*)d_in[13];
    const float* be0   = (const float*)d_in[14];
    const float* W1    = (const float*)d_in[15];
    const float* as1   = (const float*)d_in[16];
    const float* ad1   = (const float*)d_in[17];
    const float* bias1 = (const float*)d_in[18];
    const float* g1    = (const float*)d_in[19];
    const float* be1   = (const float*)d_in[20];
    const float* W2    = (const float*)d_in[21];
    const float* as2   = (const float*)d_in[22];
    const float* ad2   = (const float*)d_in[23];
    const float* bias2 = (const float*)d_in[24];
    const float* g2    = (const float*)d_in[25];
    const float* be2   = (const float*)d_in[26];
    const float* W_out = (const float*)d_in[27];
    const float* b_out = (const float*)d_in[28];
    float* out = (float*)d_out;

    char* wp = (char*)d_ws;
    auto alloc = [&](size_t bytes) {
        char* p = wp;
        wp += (bytes + 255) & ~(size_t)255;
        return p;
    };
    float*    B_h    = (float*)alloc((size_t)N_NODES * 128 * 4);
    ushort_t* B_hp16 = (ushort_t*)alloc((size_t)N_NODES * 128 * 2);
    ushort_t* B_h16  = (ushort_t*)alloc((size_t)N_NODES * 128 * 2);
    // union: rec (N_TOT*16B) dies before aggq (N*512*2B) is written
    char*     B_u    = (char*)alloc(52800000);
    int4*     B_rec  = (int4*)B_u;
    ushort_t* B_aggq = (ushort_t*)B_u;
    float* B_ls  = (float*)alloc((size_t)N_NODES * 4 * 4);
    float* B_ld  = (float*)alloc((size_t)N_NODES * 4 * 4);
    float* B_ls2 = (float*)alloc((size_t)N_NODES * 4 * 4);
    float* B_ld2 = (float*)alloc((size_t)N_NODES * 4 * 4);
    int*   B_off = (int*)alloc((size_t)(N_NODES + 1) * 4);
    int*   B_cnt = (int*)alloc((size_t)N_NODES * 4);
    int*   B_cur = (int*)alloc((size_t)N_NODES * 4);
    int*   B_csrc = (int*)alloc((size_t)N_TOT * 4);
    int*   B_bsum = (int*)alloc(256 * 4);
    int*   B_boff = (int*)alloc(256 * 4);
    float* B_v    = (float*)alloc(128 * 4);
    float* B_easum = (float*)alloc(32 * 4);
    float* B_aloop = (float*)alloc(4 * 4);
    float* B_us   = (float*)alloc(512 * 4);
    float* B_ud   = (float*)alloc(512 * 4);
    ushort_t* B_w2bf   = (ushort_t*)alloc(8192 * 16);
    ushort_t* B_w0bf   = (ushort_t*)alloc(2048 * 16);
    ushort_t* B_w1bf   = (ushort_t*)alloc(2048 * 16);
    ushort_t* B_woutbf = (ushort_t*)alloc(2048 * 16);
    ushort_t* B_wepbf  = (ushort_t*)alloc(128 * 16);

    hipMemsetAsync(B_cnt, 0, (size_t)N_NODES * 4, stream);
    hipMemsetAsync(B_cur, 0, (size_t)N_NODES * 4, stream);
    hipMemsetAsync(B_easum, 0, 32 * 4, stream);

    const int NB = (N_NODES + 255) / 256;
    int eblocks = (N_TOT + 255) / 256;
    k_count<<<eblocks, 256, 0, stream>>>(ei, B_cnt);
    k_scan1<<<NB, 256, 0, stream>>>(B_cnt, B_bsum);
    k_scan2<<<1, 256, 0, stream>>>(B_bsum, B_boff);
    k_scan3<<<NB, 256, 0, stream>>>(B_cnt, B_boff, B_off);

    k_v<<<1, 128, 0, stream>>>(We0, ae0, B_v);
    k_wepbf<<<1, 128, 0, stream>>>(epW, B_wepbf);
    // alpha + CSR scatter of real-edge records (needs off/cur)
    k_alpha_mfma<<<N_EDGES / 256, 256, 0, stream>>>(eattr, B_wepbf, epb, B_v,
                                                    ei, B_off, B_cur, B_rec, B_easum);
    k_aloop<<<1, 64, 0, stream>>>(B_easum, B_v, B_aloop);
    k_fill_loop<<<NB, 256, 0, stream>>>(B_off, B_cur, B_aloop, B_rec);
    k_extract<<<eblocks, 256, 0, stream>>>(B_rec, B_csrc);

    k_w2bf<<<32, 256, 0, stream>>>(W2, B_w2bf);
    k_wbf<<<8, 256, 0, stream>>>(W0, B_w0bf);
    k_wbf<<<8, 256, 0, stream>>>(W1, B_w1bf);
    k_wbf<<<8, 256, 0, stream>>>(W_out, B_woutbf);
    k_u<<<2, 256, 0, stream>>>(W2, as2, ad2, B_us, B_ud);
    k_proj_in<<<N_NODES / 4, 128, 0, stream>>>(x, W_in, b_in, B_h, B_h16);

    const int PB = (N_NODES + 63) / 64;
    // layer 0 (agg fused with residual+LN)
    k_proj_attn_mfma<<<PB, 256, 0, stream>>>(B_h16, B_w0bf, as0, ad0, B_hp16, B_ls, B_ld);
    k_agg32<true><<<N_NODES / 4, 256, 0, stream>>>(B_off, B_rec, nullptr, B_hp16, B_ls, B_ld,
                                                   bias0, g0, be0, B_h, B_h16,
                                                   nullptr, nullptr, nullptr, nullptr);

    // layer 1 (agg + LN + fused layer-2 ls/ld)
    k_proj_attn_mfma<<<PB, 256, 0, stream>>>(B_h16, B_w1bf, as1, ad1, B_hp16, B_ls, B_ld);
    k_agg32<false><<<N_NODES / 4, 256, 0, stream>>>(B_off, nullptr, B_csrc, B_hp16, B_ls, B_ld,
                                                    bias1, g1, be1, B_h, B_h16,
                                                    B_us, B_ud, B_ls2, B_ld2);

    // layer 2: aggregate inputs, then fused {W2-proj + LN + W_out-proj} via MFMA
    k_agg2<<<N_NODES / 4, 256, 0, stream>>>(B_off, B_csrc, B_h16, B_ls2, B_ld2, B_aggq);
    k_gemm_post<<<(N_NODES + 63) / 64, 256, 0, stream>>>(B_aggq, B_w2bf, bias2, g2, be2,
                                                         B_h, B_woutbf, b_out, out);
}

// Round 12
// 552.839 us; speedup vs baseline: 1.1165x; 1.1165x over previous
//
#include <hip/hip_runtime.h>
#include <hip/hip_bf16.h>
#include <math.h>

#define N_NODES 50000
#define N_EDGES 1600000
#define N_TOT   (N_EDGES + N_NODES)
#define NBKT 64

typedef unsigned short ushort_t;
typedef short short8v __attribute__((ext_vector_type(8)));
typedef float f32x4 __attribute__((ext_vector_type(4)));

__device__ __forceinline__ float lrelu(float x) { return x > 0.f ? x : 0.2f * x; }
__device__ __forceinline__ float bf2f(ushort_t u) { return __uint_as_float((unsigned)u << 16); }
__device__ __forceinline__ ushort_t f2bf(float f) {
    union { __hip_bfloat16 b; ushort_t u; } cv;
    cv.b = __float2bfloat16(f);
    return cv.u;
}

// ---------------- CSR build ----------------
__global__ void k_count(const int* __restrict__ ei, int* __restrict__ cnt) {
    int e = blockIdx.x * 256 + threadIdx.x;
    if (e >= N_TOT) return;
    int dst = (e < N_EDGES) ? ei[N_EDGES + e] : (e - N_EDGES);
    atomicAdd(&cnt[dst], 1);
}

__global__ void k_scan1(const int* __restrict__ cnt, int* __restrict__ bsum) {
    __shared__ int ws[4];
    int g = blockIdx.x * 256 + threadIdx.x;
    int lane = threadIdx.x & 63, wv = threadIdx.x >> 6;
    int x = (g < N_NODES) ? cnt[g] : 0;
#pragma unroll
    for (int s = 1; s < 64; s <<= 1) x += __shfl_xor(x, s, 64);
    if (lane == 0) ws[wv] = x;
    __syncthreads();
    if (threadIdx.x == 0) bsum[blockIdx.x] = ws[0] + ws[1] + ws[2] + ws[3];
}

__global__ void k_scan2(const int* __restrict__ bsum, int* __restrict__ boff) {
    __shared__ int ws[4];
    const int NB = (N_NODES + 255) / 256;
    int t = threadIdx.x, lane = t & 63, wv = t >> 6;
    int v = (t < NB) ? bsum[t] : 0;
    int x = v;
#pragma unroll
    for (int s = 1; s < 64; s <<= 1) { int tt = __shfl_up(x, s, 64); if (lane >= s) x += tt; }
    if (lane == 63) ws[wv] = x;
    __syncthreads();
    int add = 0;
#pragma unroll
    for (int w = 0; w < 4; ++w) add += (w < wv) ? ws[w] : 0;
    x += add;
    if (t < NB) boff[t] = x - v;   // exclusive
}

__global__ void k_scan3(const int* __restrict__ cnt, const int* __restrict__ boff,
                        int* __restrict__ off) {
    __shared__ int ws[4];
    int g = blockIdx.x * 256 + threadIdx.x;
    int lane = threadIdx.x & 63, wv = threadIdx.x >> 6;
    int v = (g < N_NODES) ? cnt[g] : 0;
    int x = v;
#pragma unroll
    for (int s = 1; s < 64; s <<= 1) { int tt = __shfl_up(x, s, 64); if (lane >= s) x += tt; }
    if (lane == 63) ws[wv] = x;
    __syncthreads();
    int add = 0;
#pragma unroll
    for (int w = 0; w < 4; ++w) add += (w < wv) ? ws[w] : 0;
    x += add;
    if (g < N_NODES) off[g + 1] = boff[blockIdx.x] + x;
    if (g == 0) off[0] = 0;
}

// self-loop records: {n, aloop packed}
__global__ void k_fill_loop(const int* __restrict__ off, int* __restrict__ cur,
                            const float* __restrict__ aloop, int4* __restrict__ rec) {
    int n = blockIdx.x * 256 + threadIdx.x;
    if (n >= N_NODES) return;
    unsigned ax = (unsigned)f2bf(aloop[0]) | ((unsigned)f2bf(aloop[1]) << 16);
    unsigned ay = (unsigned)f2bf(aloop[2]) | ((unsigned)f2bf(aloop[3]) << 16);
    int pos = off[n] + atomicAdd(&cur[n], 1);
    rec[pos] = make_int4(n, (int)ax, (int)ay, 0);
}

__global__ void k_extract(const int4* __restrict__ rec, int* __restrict__ csrc) {
    int p = blockIdx.x * 256 + threadIdx.x;
    if (p < N_TOT) csrc[p] = rec[p].x;
}

// ---------------- edge attention precompute ----------------
__global__ void k_v(const float* __restrict__ We0, const float* __restrict__ ae0,
                    float* __restrict__ v) {
    int t = threadIdx.x;            // 0..127
    int h = t >> 5, k = t & 31;
    float s = 0.f;
    for (int c = 0; c < 32; ++c) s += We0[k * 128 + h * 32 + c] * ae0[h * 32 + c];
    v[h * 32 + k] = s;
}

// epW (32x32 row-major) -> bf16 MFMA fragments (used as A = epW^T tiles)
__global__ void k_wepbf(const float* __restrict__ epW, ushort_t* __restrict__ Bp) {
    int t = threadIdx.x;              // 0..127
    if (t >= 128) return;
    int lane = t & 63, ct = t >> 6;
    int j = ct * 16 + (lane & 15);
    int kbase = (lane >> 4) * 8;
    ushort_t o[8];
#pragma unroll
    for (int jj = 0; jj < 8; ++jj) o[jj] = f2bf(epW[(kbase + jj) * 32 + j]);
    ((uint4*)Bp)[t] = *(uint4*)o;
}

// MFMA edge-attention (transposed) + fused CSR scatter; easum via 64-way bucketed atomics.
__global__ void k_alpha_mfma(const float* __restrict__ eattr, const ushort_t* __restrict__ Aw,
                             const float* __restrict__ epb, const float* __restrict__ v,
                             const int* __restrict__ ei, const int* __restrict__ off,
                             int* __restrict__ cur, int4* __restrict__ rec,
                             float* __restrict__ easum_part) {
    __shared__ float sums[4][32];
    int tid = threadIdx.x;
    int lane = tid & 63, wv = tid >> 6;
    int c = lane & 15, g = lane >> 4;   // c = edge column, g = channel group
    int e0base = blockIdx.x * 256 + wv * 64;

    // hoisted: CSR slot reservation
    int e = e0base + lane;
    int src = ei[e], dst = ei[N_EDGES + e];
    int pos = off[dst] + atomicAdd(&cur[dst], 1);

    // hoisted: stage all eattr tiles
    float4 F0[4], F1[4];
#pragma unroll
    for (int t = 0; t < 4; ++t) {
        const float4* ap = (const float4*)(eattr + (size_t)(e0base + t * 16 + c) * 32 + g * 8);
        F0[t] = ap[0];
        F1[t] = ap[1];
    }

    short8v a0 = ((const short8v*)Aw)[lane];        // channels 0-15
    short8v a1 = ((const short8v*)Aw)[64 + lane];   // channels 16-31

    float eb0[4], eb1[4], vv0[4][4], vv1[4][4];
#pragma unroll
    for (int r = 0; r < 4; ++r) {
        eb0[r] = epb[g * 4 + r];
        eb1[r] = epb[16 + g * 4 + r];
#pragma unroll
        for (int h = 0; h < 4; ++h) {
            vv0[h][r] = v[h * 32 + g * 4 + r];
            vv1[h][r] = v[h * 32 + 16 + g * 4 + r];
        }
    }

    float se0[4] = {0.f, 0.f, 0.f, 0.f}, se1[4] = {0.f, 0.f, 0.f, 0.f};
    uint2 oo0, oo1, oo2, oo3;
#pragma unroll
    for (int t = 0; t < 4; ++t) {
        float4 f0 = F0[t], f1 = F1[t];
        ushort_t ai[8];
        ai[0] = f2bf(f0.x); ai[1] = f2bf(f0.y); ai[2] = f2bf(f0.z); ai[3] = f2bf(f0.w);
        ai[4] = f2bf(f1.x); ai[5] = f2bf(f1.y); ai[6] = f2bf(f1.z); ai[7] = f2bf(f1.w);
        short8v b = *(short8v*)ai;                  // B = eattr^T fragment
        f32x4 acc0 = (f32x4){0.f, 0.f, 0.f, 0.f};
        f32x4 acc1 = (f32x4){0.f, 0.f, 0.f, 0.f};
        acc0 = __builtin_amdgcn_mfma_f32_16x16x32_bf16(a0, b, acc0, 0, 0, 0);
        acc1 = __builtin_amdgcn_mfma_f32_16x16x32_bf16(a1, b, acc1, 0, 0, 0);
        float p0 = 0.f, p1 = 0.f, p2 = 0.f, p3 = 0.f;
#pragma unroll
        for (int r = 0; r < 4; ++r) {
            float u0 = fmaxf(acc0[r] + eb0[r], 0.f);
            float u1 = fmaxf(acc1[r] + eb1[r], 0.f);
            se0[r] += u0; se1[r] += u1;
            p0 += u0 * vv0[0][r] + u1 * vv1[0][r];
            p1 += u0 * vv0[1][r] + u1 * vv1[1][r];
            p2 += u0 * vv0[2][r] + u1 * vv1[2][r];
            p3 += u0 * vv0[3][r] + u1 * vv1[3][r];
        }
        p0 += __shfl_xor(p0, 16, 64); p0 += __shfl_xor(p0, 32, 64);
        p1 += __shfl_xor(p1, 16, 64); p1 += __shfl_xor(p1, 32, 64);
        p2 += __shfl_xor(p2, 16, 64); p2 += __shfl_xor(p2, 32, 64);
        p3 += __shfl_xor(p3, 16, 64); p3 += __shfl_xor(p3, 32, 64);
        uint2 o;
        o.x = (unsigned)f2bf(p0) | ((unsigned)f2bf(p1) << 16);
        o.y = (unsigned)f2bf(p2) | ((unsigned)f2bf(p3) << 16);
        if (t == 0) oo0 = o; else if (t == 1) oo1 = o; else if (t == 2) oo2 = o; else oo3 = o;
    }
    uint2 o = oo0;
    o.x = (g == 1) ? oo1.x : o.x; o.y = (g == 1) ? oo1.y : o.y;
    o.x = (g == 2) ? oo2.x : o.x; o.y = (g == 2) ? oo2.y : o.y;
    o.x = (g == 3) ? oo3.x : o.x; o.y = (g == 3) ? oo3.y : o.y;
    rec[pos] = make_int4(src, (int)o.x, (int)o.y, 0);

    // easum partials
#pragma unroll
    for (int r = 0; r < 4; ++r) {
#pragma unroll
        for (int m = 1; m < 16; m <<= 1) {
            se0[r] += __shfl_xor(se0[r], m, 64);
            se1[r] += __shfl_xor(se1[r], m, 64);
        }
    }
    if (c == 0) {
#pragma unroll
        for (int r = 0; r < 4; ++r) {
            sums[wv][g * 4 + r] = se0[r];
            sums[wv][16 + g * 4 + r] = se1[r];
        }
    }
    __syncthreads();
    if (tid < 32) {
        // 64-way bucketed: chain depth per address drops 6250 -> ~98
        atomicAdd(&easum_part[(blockIdx.x & (NBKT - 1)) * 32 + tid],
                  sums[0][tid] + sums[1][tid] + sums[2][tid] + sums[3][tid]);
    }
}

// reduce easum buckets, then aloop[h] = mean(ea) . v[h]
__global__ void k_aloop(const float* __restrict__ easum_part, const float* __restrict__ v,
                        float* __restrict__ aloop) {
    __shared__ float es[32];
    int t = threadIdx.x;
    if (t < 32) {
        float s = 0.f;
        for (int b = 0; b < NBKT; ++b) s += easum_part[b * 32 + t];
        es[t] = s;
    }
    __syncthreads();
    if (t < 4) {
        float s = 0.f;
        for (int c = 0; c < 32; ++c) s += (es[c] * (1.f / (float)N_EDGES)) * v[t * 32 + c];
        aloop[t] = s;
    }
}

// ---------------- weight conversion: 128x128 f32 -> MFMA B-fragment bf16 ----------------
__global__ void k_wbf(const float* __restrict__ W, ushort_t* __restrict__ Bp) {
    int t = blockIdx.x * 256 + threadIdx.x;   // 0..2047
    if (t >= 2048) return;
    int lane = t & 63;
    int ct = (t >> 6) & 7;
    int kb = t >> 9;
    int j = ct * 16 + (lane & 15);
    int kbase = kb * 32 + (lane >> 4) * 8;
    ushort_t o[8];
#pragma unroll
    for (int jj = 0; jj < 8; ++jj) o[jj] = f2bf(W[(kbase + jj) * 128 + j]);
    ((uint4*)Bp)[t] = *(uint4*)o;
}

// W2 (512x128 effective) -> B-fragments
__global__ void k_w2bf(const float* __restrict__ W2, ushort_t* __restrict__ Bp) {
    int t = blockIdx.x * 256 + threadIdx.x;   // 0..8191
    if (t >= 8192) return;
    int lane = t & 63;
    int ct = (t >> 6) & 7;
    int kb = t >> 9;
    int j = ct * 16 + (lane & 15);
    int kbase = kb * 32 + (lane >> 4) * 8;
    ushort_t o[8];
#pragma unroll
    for (int jj = 0; jj < 8; ++jj) {
        int kk = kbase + jj;
        int h = kk >> 7, kp = kk & 127;
        o[jj] = f2bf(W2[kp * 512 + h * 128 + j]);
    }
    ((uint4*)Bp)[t] = *(uint4*)o;
}

// ---------------- GEMMs ----------------
__global__ void k_proj_in(const float* __restrict__ x, const float* __restrict__ W,
                          const float* __restrict__ b, float* __restrict__ h,
                          ushort_t* __restrict__ h16) {
    int j = threadIdx.x;               // 0..127
    int n0 = blockIdx.x * 4;
    const float* x0 = x + (size_t)n0 * 64;
    float a0 = 0.f, a1 = 0.f, a2 = 0.f, a3 = 0.f;
    for (int k = 0; k < 64; ++k) {
        float w = W[k * 128 + j];
        a0 += x0[k] * w;
        a1 += x0[64 + k] * w;
        a2 += x0[128 + k] * w;
        a3 += x0[192 + k] * w;
    }
    float bb = b[j];
    a0 = fmaxf(a0 + bb, 0.f); a1 = fmaxf(a1 + bb, 0.f);
    a2 = fmaxf(a2 + bb, 0.f); a3 = fmaxf(a3 + bb, 0.f);
    h[(size_t)(n0 + 0) * 128 + j] = a0;
    h[(size_t)(n0 + 1) * 128 + j] = a1;
    h[(size_t)(n0 + 2) * 128 + j] = a2;
    h[(size_t)(n0 + 3) * 128 + j] = a3;
    h16[(size_t)(n0 + 0) * 128 + j] = f2bf(a0);
    h16[(size_t)(n0 + 1) * 128 + j] = f2bf(a1);
    h16[(size_t)(n0 + 2) * 128 + j] = f2bf(a2);
    h16[(size_t)(n0 + 3) * 128 + j] = f2bf(a3);
}

// MFMA projection: hp16 = bf16(h16 @ Wbf); fused ls/ld
__global__ void k_proj_attn_mfma(const ushort_t* __restrict__ h16, const ushort_t* __restrict__ Bp,
                                 const float* __restrict__ as_, const float* __restrict__ ad_,
                                 ushort_t* __restrict__ hp16, float* __restrict__ ls,
                                 float* __restrict__ ld) {
    int tid = threadIdx.x;
    int lane = tid & 63, wid = tid >> 6;
    int n0 = blockIdx.x * 64 + wid * 16;
    int arow = n0 + (lane & 15);
    int arc = arow < N_NODES ? arow : 0;
    int koff = (lane >> 4) * 8;
    const short8v* ap = (const short8v*)(h16 + (size_t)arc * 128 + koff);
    const short8v* bp = (const short8v*)Bp;

    f32x4 acc[8];
#pragma unroll
    for (int ct = 0; ct < 8; ++ct) acc[ct] = (f32x4){0.f, 0.f, 0.f, 0.f};
#pragma unroll
    for (int kb = 0; kb < 4; ++kb) {
        short8v a = ap[kb * 4];
#pragma unroll
        for (int ct = 0; ct < 8; ++ct) {
            short8v b = bp[(kb * 8 + ct) * 64 + lane];
            acc[ct] = __builtin_amdgcn_mfma_f32_16x16x32_bf16(a, b, acc[ct], 0, 0, 0);
        }
    }

    int q = lane >> 4, c = lane & 15;
#pragma unroll
    for (int reg = 0; reg < 4; ++reg) {
        int row = n0 + q * 4 + reg;
        if (row < N_NODES) {
#pragma unroll
            for (int ct = 0; ct < 8; ++ct)
                hp16[(size_t)row * 128 + ct * 16 + c] = f2bf(acc[ct][reg]);
        }
    }
#pragma unroll
    for (int h = 0; h < 4; ++h) {
        float alo = as_[h * 32 + c], ahi = as_[h * 32 + 16 + c];
        float dlo = ad_[h * 32 + c], dhi = ad_[h * 32 + 16 + c];
#pragma unroll
        for (int reg = 0; reg < 4; ++reg) {
            float s = acc[2 * h][reg] * alo + acc[2 * h + 1][reg] * ahi;
            float d = acc[2 * h][reg] * dlo + acc[2 * h + 1][reg] * dhi;
#pragma unroll
            for (int m = 1; m < 16; m <<= 1) {
                s += __shfl_xor(s, m, 64);
                d += __shfl_xor(d, m, 64);
            }
            int row = n0 + q * 4 + reg;
            if (c == 0 && row < N_NODES) {
                ls[row * 4 + h] = s;
                ld[row * 4 + h] = d;
            }
        }
    }
}

// u_s[h,k] = sum_c W2[k, h*128+c] * as2[h,c] (and u_d)
__global__ void k_u(const float* __restrict__ W2, const float* __restrict__ as2,
                    const float* __restrict__ ad2, float* __restrict__ us,
                    float* __restrict__ ud) {
    int t = blockIdx.x * 256 + threadIdx.x;
    if (t >= 512) return;
    int h = t >> 7, k = t & 127;
    float ss = 0.f, dd = 0.f;
    for (int c = 0; c < 128; ++c) {
        float w = W2[k * 512 + h * 128 + c];
        ss += w * as2[h * 128 + c];
        dd += w * ad2[h * 128 + c];
    }
    us[h * 128 + k] = ss;
    ud[h * 128 + k] = dd;
}

// ---- GAT aggregation + fused residual/LayerNorm (+ optional ls2/ld2), 4 nodes/block --
template <bool L0>
__global__ void k_agg32(const int* __restrict__ off, const int4* __restrict__ rec,
                        const int* __restrict__ csrc,
                        const ushort_t* __restrict__ hp16, const float* __restrict__ ls,
                        const float* __restrict__ ld,
                        const float* __restrict__ bias, const float* __restrict__ g,
                        const float* __restrict__ be,
                        float* h, ushort_t* __restrict__ h16,
                        const float* __restrict__ us, const float* __restrict__ ud,
                        float* __restrict__ ls2, float* __restrict__ ld2) {
    __shared__ float swt[4][64][4];
    __shared__ int ssrc[4][64];
    int wv = threadIdx.x >> 6, lane = threadIdx.x & 63;
    int n = blockIdx.x * 4 + wv;
    int beg = off[n], deg = off[n + 1] - beg;
    float4 ldv = *(const float4*)(ld + n * 4);

    int hsel = lane >> 4;   // head of channels {2*lane, 2*lane+1}
    float acc0 = 0.f, acc1 = 0.f;
    float d0 = 0.f, d1 = 0.f, d2 = 0.f, d3 = 0.f;
    for (int base = 0; base < deg; base += 64) {
        int i = base + lane;
        float w0 = 0, w1 = 0, w2 = 0, w3 = 0;
        int s = 0;
        if (i < deg) {
            float a0 = 0, a1 = 0, a2 = 0, a3 = 0;
            if (L0) {
                int4 r = rec[beg + i];
                s = r.x;
                a0 = bf2f((ushort_t)((unsigned)r.y & 0xffffu));
                a1 = bf2f((ushort_t)((unsigned)r.y >> 16));
                a2 = bf2f((ushort_t)((unsigned)r.z & 0xffffu));
                a3 = bf2f((ushort_t)((unsigned)r.z >> 16));
            } else {
                s = csrc[beg + i];
            }
            float4 lsv = *(const float4*)(ls + s * 4);
            w0 = __expf(lrelu(lsv.x + ldv.x + a0)); d0 += w0;
            w1 = __expf(lrelu(lsv.y + ldv.y + a1)); d1 += w1;
            w2 = __expf(lrelu(lsv.z + ldv.z + a2)); d2 += w2;
            w3 = __expf(lrelu(lsv.w + ldv.w + a3)); d3 += w3;
        }
        *(float4*)&swt[wv][lane][0] = make_float4(w0, w1, w2, w3);
        ssrc[wv][lane] = s;
        int cnt = min(64, deg - base);
        int jj = 0;
        for (; jj + 4 <= cnt; jj += 4) {
            float wA = swt[wv][jj + 0][hsel]; int sA = ssrc[wv][jj + 0];
            float wB = swt[wv][jj + 1][hsel]; int sB = ssrc[wv][jj + 1];
            float wC = swt[wv][jj + 2][hsel]; int sC = ssrc[wv][jj + 2];
            float wD = swt[wv][jj + 3][hsel]; int sD = ssrc[wv][jj + 3];
            ushort2 vA = ((const ushort2*)(hp16 + (size_t)sA * 128))[lane];
            ushort2 vB = ((const ushort2*)(hp16 + (size_t)sB * 128))[lane];
            ushort2 vC = ((const ushort2*)(hp16 + (size_t)sC * 128))[lane];
            ushort2 vD = ((const ushort2*)(hp16 + (size_t)sD * 128))[lane];
            acc0 += bf2f(vA.x) * wA; acc1 += bf2f(vA.y) * wA;
            acc0 += bf2f(vB.x) * wB; acc1 += bf2f(vB.y) * wB;
            acc0 += bf2f(vC.x) * wC; acc1 += bf2f(vC.y) * wC;
            acc0 += bf2f(vD.x) * wD; acc1 += bf2f(vD.y) * wD;
        }
        for (; jj < cnt; ++jj) {
            float wA = swt[wv][jj][hsel];
            int sA = ssrc[wv][jj];
            ushort2 vA = ((const ushort2*)(hp16 + (size_t)sA * 128))[lane];
            acc0 += bf2f(vA.x) * wA;
            acc1 += bf2f(vA.y) * wA;
        }
    }
#pragma unroll
    for (int k = 1; k < 64; k <<= 1) {
        d0 += __shfl_xor(d0, k, 64); d1 += __shfl_xor(d1, k, 64);
        d2 += __shfl_xor(d2, k, 64); d3 += __shfl_xor(d3, k, 64);
    }
    float dsel = (hsel == 0) ? d0 : (hsel == 1) ? d1 : (hsel == 2) ? d2 : d3;
    float2 bb = ((const float2*)bias)[lane];
    size_t hbase = (size_t)n * 128;
    float2 hres = ((const float2*)(h + hbase))[lane];
    float v0 = acc0 / dsel + bb.x + hres.x;
    float v1 = acc1 / dsel + bb.y + hres.y;
    float s = v0 + v1, ss = v0 * v0 + v1 * v1;
#pragma unroll
    for (int k = 1; k < 64; k <<= 1) { s += __shfl_xor(s, k, 64); ss += __shfl_xor(ss, k, 64); }
    float mean = s * (1.f / 128.f);
    float var = ss * (1.f / 128.f) - mean * mean;
    float inv = rsqrtf(var + 1e-5f);
    float2 gg = ((const float2*)g)[lane];
    float2 bee = ((const float2*)be)[lane];
    float r0 = (v0 - mean) * inv * gg.x + bee.x;
    float r1 = (v1 - mean) * inv * gg.y + bee.y;
    ((float2*)(h + hbase))[lane] = make_float2(r0, r1);
    ushort2 o16; o16.x = f2bf(r0); o16.y = f2bf(r1);
    ((ushort2*)(h16 + hbase))[lane] = o16;

    if (!L0) {
        float sh[4], dh[4];
#pragma unroll
        for (int hh = 0; hh < 4; ++hh) {
            float2 u2 = ((const float2*)(us + hh * 128))[lane];
            float2 w2 = ((const float2*)(ud + hh * 128))[lane];
            sh[hh] = r0 * u2.x + r1 * u2.y;
            dh[hh] = r0 * w2.x + r1 * w2.y;
        }
#pragma unroll
        for (int k = 1; k < 64; k <<= 1) {
#pragma unroll
            for (int hh = 0; hh < 4; ++hh) {
                sh[hh] += __shfl_xor(sh[hh], k, 64);
                dh[hh] += __shfl_xor(dh[hh], k, 64);
            }
        }
        if (lane == 0) {
#pragma unroll
            for (int hh = 0; hh < 4; ++hh) {
                ls2[n * 4 + hh] = sh[hh];
                ld2[n * 4 + hh] = dh[hh];
            }
        }
    }
}

// ---------- layer-2 aggregation: single-pass, gather INPUT h (bf16), 4 nodes/block --
__global__ void k_agg2(const int* __restrict__ off, const int* __restrict__ csrc,
                       const ushort_t* __restrict__ h16, const float* __restrict__ ls,
                       const float* __restrict__ ld, ushort_t* __restrict__ aggq) {
    __shared__ float4 swt[4][64];
    __shared__ int ssrc[4][64];
    int wv = threadIdx.x >> 6, lane = threadIdx.x & 63;
    int n = blockIdx.x * 4 + wv;
    int beg = off[n], deg = off[n + 1] - beg;
    float4 ldv = *(const float4*)(ld + n * 4);

    float a00 = 0, a01 = 0, a10 = 0, a11 = 0, a20 = 0, a21 = 0, a30 = 0, a31 = 0;
    float d0 = 0, d1 = 0, d2 = 0, d3 = 0;
    for (int base = 0; base < deg; base += 64) {
        int i = base + lane;
        float w0 = 0, w1 = 0, w2 = 0, w3 = 0;
        int s = 0;
        if (i < deg) {
            s = csrc[beg + i];
            float4 lsv = *(const float4*)(ls + s * 4);
            w0 = __expf(lrelu(lsv.x + ldv.x)); d0 += w0;
            w1 = __expf(lrelu(lsv.y + ldv.y)); d1 += w1;
            w2 = __expf(lrelu(lsv.z + ldv.z)); d2 += w2;
            w3 = __expf(lrelu(lsv.w + ldv.w)); d3 += w3;
        }
        swt[wv][lane] = make_float4(w0, w1, w2, w3);
        ssrc[wv][lane] = s;
        int cnt = min(64, deg - base);
        int jj = 0;
        for (; jj + 2 <= cnt; jj += 2) {
            float4 wA = swt[wv][jj];     int sA = ssrc[wv][jj];
            float4 wB = swt[wv][jj + 1]; int sB = ssrc[wv][jj + 1];
            ushort2 vA = ((const ushort2*)(h16 + (size_t)sA * 128))[lane];
            ushort2 vB = ((const ushort2*)(h16 + (size_t)sB * 128))[lane];
            float fA0 = bf2f(vA.x), fA1 = bf2f(vA.y);
            float fB0 = bf2f(vB.x), fB1 = bf2f(vB.y);
            a00 += fA0 * wA.x; a01 += fA1 * wA.x;
            a10 += fA0 * wA.y; a11 += fA1 * wA.y;
            a20 += fA0 * wA.z; a21 += fA1 * wA.z;
            a30 += fA0 * wA.w; a31 += fA1 * wA.w;
            a00 += fB0 * wB.x; a01 += fB1 * wB.x;
            a10 += fB0 * wB.y; a11 += fB1 * wB.y;
            a20 += fB0 * wB.z; a21 += fB1 * wB.z;
            a30 += fB0 * wB.w; a31 += fB1 * wB.w;
        }
        for (; jj < cnt; ++jj) {
            float4 w4 = swt[wv][jj];
            int sj = ssrc[wv][jj];
            ushort2 v = ((const ushort2*)(h16 + (size_t)sj * 128))[lane];
            float f0 = bf2f(v.x), f1 = bf2f(v.y);
            a00 += f0 * w4.x; a01 += f1 * w4.x;
            a10 += f0 * w4.y; a11 += f1 * w4.y;
            a20 += f0 * w4.z; a21 += f1 * w4.z;
            a30 += f0 * w4.w; a31 += f1 * w4.w;
        }
    }
#pragma unroll
    for (int k = 1; k < 64; k <<= 1) {
        d0 += __shfl_xor(d0, k, 64); d1 += __shfl_xor(d1, k, 64);
        d2 += __shfl_xor(d2, k, 64); d3 += __shfl_xor(d3, k, 64);
    }
    float r0 = 0.25f / d0, r1 = 0.25f / d1, r2 = 0.25f / d2, r3 = 0.25f / d3;
    ushort_t* base_p = aggq + (size_t)n * 512;
    ushort2 w;
    w.x = f2bf(a00 * r0); w.y = f2bf(a01 * r0); ((ushort2*)(base_p      ))[lane] = w;
    w.x = f2bf(a10 * r1); w.y = f2bf(a11 * r1); ((ushort2*)(base_p + 128))[lane] = w;
    w.x = f2bf(a20 * r2); w.y = f2bf(a21 * r2); ((ushort2*)(base_p + 256))[lane] = w;
    w.x = f2bf(a30 * r3); w.y = f2bf(a31 * r3); ((ushort2*)(base_p + 384))[lane] = w;
}

// --- MFMA GEMM: t = LN(aggq @ W2bf + bias2 + hbuf); out = t @ W_out + b_out (fused) ---
__global__ void k_gemm_post(const ushort_t* __restrict__ aggq, const ushort_t* __restrict__ Bp,
                            const float* __restrict__ bias, const float* __restrict__ g,
                            const float* __restrict__ be, const float* __restrict__ hbuf,
                            const ushort_t* __restrict__ Wout_bp, const float* __restrict__ b_out,
                            float* __restrict__ out) {
    __shared__ ushort_t tile[4][16][136];   // per-wave 16x128 bf16, padded
    int tid = threadIdx.x;
    int lane = tid & 63, wid = tid >> 6;
    int n0 = blockIdx.x * 64 + wid * 16;
    int arow = n0 + (lane & 15);
    int arc = arow < N_NODES ? arow : 0;
    int koff = (lane >> 4) * 8;

    const short8v* ap = (const short8v*)(aggq + (size_t)arc * 512 + koff);
    const short8v* bp = (const short8v*)Bp;

    f32x4 acc[8];
#pragma unroll
    for (int ct = 0; ct < 8; ++ct) acc[ct] = (f32x4){0.f, 0.f, 0.f, 0.f};
#pragma unroll
    for (int kb = 0; kb < 16; ++kb) {
        short8v a = ap[kb * 4];
#pragma unroll
        for (int ct = 0; ct < 8; ++ct) {
            short8v b = bp[(kb * 8 + ct) * 64 + lane];
            acc[ct] = __builtin_amdgcn_mfma_f32_16x16x32_bf16(a, b, acc[ct], 0, 0, 0);
        }
    }

    int q = lane >> 4, c = lane & 15;
    float gv[8], bev[8], bv[8];
#pragma unroll
    for (int ct = 0; ct < 8; ++ct) {
        int col = ct * 16 + c;
        gv[ct] = g[col]; bev[ct] = be[col]; bv[ct] = bias[col];
    }
#pragma unroll
    for (int reg = 0; reg < 4; ++reg) {
        int row = n0 + q * 4 + reg;
        int rc = row < N_NODES ? row : 0;
        float v[8];
        float s = 0.f, ss = 0.f;
#pragma unroll
        for (int ct = 0; ct < 8; ++ct) {
            float val = acc[ct][reg] + bv[ct] + hbuf[(size_t)rc * 128 + ct * 16 + c];
            v[ct] = val; s += val; ss += val * val;
        }
#pragma unroll
        for (int m = 1; m < 16; m <<= 1) {
            s += __shfl_xor(s, m, 64);
            ss += __shfl_xor(ss, m, 64);
        }
        float mean = s * (1.f / 128.f);
        float var = ss * (1.f / 128.f) - mean * mean;
        float inv = rsqrtf(var + 1e-5f);
        int lrow = q * 4 + reg;
#pragma unroll
        for (int ct = 0; ct < 8; ++ct)
            tile[wid][lrow][ct * 16 + c] = f2bf((v[ct] - mean) * inv * gv[ct] + bev[ct]);
    }

    const short8v* wp = (const short8v*)Wout_bp;
    f32x4 acc2[8];
#pragma unroll
    for (int ct = 0; ct < 8; ++ct) acc2[ct] = (f32x4){0.f, 0.f, 0.f, 0.f};
#pragma unroll
    for (int kb = 0; kb < 4; ++kb) {
        short8v a = *(const short8v*)&tile[wid][lane & 15][kb * 32 + koff];
#pragma unroll
        for (int ct = 0; ct < 8; ++ct) {
            short8v b = wp[(kb * 8 + ct) * 64 + lane];
            acc2[ct] = __builtin_amdgcn_mfma_f32_16x16x32_bf16(a, b, acc2[ct], 0, 0, 0);
        }
    }
    float bo[8];
#pragma unroll
    for (int ct = 0; ct < 8; ++ct) bo[ct] = b_out[ct * 16 + c];
#pragma unroll
    for (int reg = 0; reg < 4; ++reg) {
        int row = n0 + q * 4 + reg;
        if (row < N_NODES) {
#pragma unroll
            for (int ct = 0; ct < 8; ++ct)
                out[(size_t)row * 128 + ct * 16 + c] = acc2[ct][reg] + bo[ct];
        }
    }
}

extern "C" void kernel_launch(void* const* d_in, const int* in_sizes, int n_in,
                              void* d_out, int out_size, void* d_ws, size_t ws_size,
                              hipStream_t stream) {
    const float* x     = (const float*)d_in[0];
    const int*   ei    = (const int*)d_in[1];
    const float* eattr = (const float*)d_in[2];
    const float* W_in  = (const float*)d_in[3];
    const float* b_in  = (const float*)d_in[4];
    const float* epW   = (const float*)d_in[5];
    const float* epb   = (const float*)d_in[6];
    const float* W0    = (const float*)d_in[7];
    const float* as0   = (const float*)d_in[8];
    const float* ad0   = (const float*)d_in[9];
    const float* We0   = (const float*)d_in[10];
    const float* ae0   = (const float*)d_in[11];
    const float* bias0 = (const float*)d_in[12];
    const float* g0    = (const float*)d_in[13];
    const float* be0   = (const float*)d_in[14];
    const float* W1    = (const float*)d_in[15];
    const float* as1   = (const float*)d_in[16];
    const float* ad1   = (const float*)d_in[17];
    const float* bias1 = (const float*)d_in[18];
    const float* g1    = (const float*)d_in[19];
    const float* be1   = (const float*)d_in[20];
    const float* W2    = (const float*)d_in[21];
    const float* as2   = (const float*)d_in[22];
    const float* ad2   = (const float*)d_in[23];
    const float* bias2 = (const float*)d_in[24];
    const float* g2    = (const float*)d_in[25];
    const float* be2   = (const float*)d_in[26];
    const float* W_out = (const float*)d_in[27];
    const float* b_out = (const float*)d_in[28];
    float* out = (float*)d_out;

    char* wp = (char*)d_ws;
    auto alloc = [&](size_t bytes) {
        char* p = wp;
        wp += (bytes + 255) & ~(size_t)255;
        return p;
    };
    float*    B_h    = (float*)alloc((size_t)N_NODES * 128 * 4);
    ushort_t* B_hp16 = (ushort_t*)alloc((size_t)N_NODES * 128 * 2);
    ushort_t* B_h16  = (ushort_t*)alloc((size_t)N_NODES * 128 * 2);
    // union: rec (N_TOT*16B) dies before aggq (N*512*2B) is written
    char*     B_u    = (char*)alloc(52800000);
    int4*     B_rec  = (int4*)B_u;
    ushort_t* B_aggq = (ushort_t*)B_u;
    float* B_ls  = (float*)alloc((size_t)N_NODES * 4 * 4);
    float* B_ld  = (float*)alloc((size_t)N_NODES * 4 * 4);
    float* B_ls2 = (float*)alloc((size_t)N_NODES * 4 * 4);
    float* B_ld2 = (float*)alloc((size_t)N_NODES * 4 * 4);
    int*   B_off = (int*)alloc((size_t)(N_NODES + 1) * 4);
    int*   B_cnt = (int*)alloc((size_t)N_NODES * 4);
    int*   B_cur = (int*)alloc((size_t)N_NODES * 4);
    int*   B_csrc = (int*)alloc((size_t)N_TOT * 4);
    int*   B_bsum = (int*)alloc(256 * 4);
    int*   B_boff = (int*)alloc(256 * 4);
    float* B_v    = (float*)alloc(128 * 4);
    float* B_easum_part = (float*)alloc(NBKT * 32 * 4);
    float* B_aloop = (float*)alloc(4 * 4);
    float* B_us   = (float*)alloc(512 * 4);
    float* B_ud   = (float*)alloc(512 * 4);
    ushort_t* B_w2bf   = (ushort_t*)alloc(8192 * 16);
    ushort_t* B_w0bf   = (ushort_t*)alloc(2048 * 16);
    ushort_t* B_w1bf   = (ushort_t*)alloc(2048 * 16);
    ushort_t* B_woutbf = (ushort_t*)alloc(2048 * 16);
    ushort_t* B_wepbf  = (ushort_t*)alloc(128 * 16);

    hipMemsetAsync(B_cnt, 0, (size_t)N_NODES * 4, stream);
    hipMemsetAsync(B_cur, 0, (size_t)N_NODES * 4, stream);
    hipMemsetAsync(B_easum_part, 0, NBKT * 32 * 4, stream);

    const int NB = (N_NODES + 255) / 256;
    int eblocks = (N_TOT + 255) / 256;
    k_count<<<eblocks, 256, 0, stream>>>(ei, B_cnt);
    k_scan1<<<NB, 256, 0, stream>>>(B_cnt, B_bsum);
    k_scan2<<<1, 256, 0, stream>>>(B_bsum, B_boff);
    k_scan3<<<NB, 256, 0, stream>>>(B_cnt, B_boff, B_off);

    k_v<<<1, 128, 0, stream>>>(We0, ae0, B_v);
    k_wepbf<<<1, 128, 0, stream>>>(epW, B_wepbf);
    k_alpha_mfma<<<N_EDGES / 256, 256, 0, stream>>>(eattr, B_wepbf, epb, B_v,
                                                    ei, B_off, B_cur, B_rec, B_easum_part);
    k_aloop<<<1, 128, 0, stream>>>(B_easum_part, B_v, B_aloop);
    k_fill_loop<<<NB, 256, 0, stream>>>(B_off, B_cur, B_aloop, B_rec);
    k_extract<<<eblocks, 256, 0, stream>>>(B_rec, B_csrc);

    k_w2bf<<<32, 256, 0, stream>>>(W2, B_w2bf);
    k_wbf<<<8, 256, 0, stream>>>(W0, B_w0bf);
    k_wbf<<<8, 256, 0, stream>>>(W1, B_w1bf);
    k_wbf<<<8, 256, 0, stream>>>(W_out, B_woutbf);
    k_u<<<2, 256, 0, stream>>>(W2, as2, ad2, B_us, B_ud);
    k_proj_in<<<N_NODES / 4, 128, 0, stream>>>(x, W_in, b_in, B_h, B_h16);

    const int PB = (N_NODES + 63) / 64;
    // layer 0 (agg fused with residual+LN)
    k_proj_attn_mfma<<<PB, 256, 0, stream>>>(B_h16, B_w0bf, as0, ad0, B_hp16, B_ls, B_ld);
    k_agg32<true><<<N_NODES / 4, 256, 0, stream>>>(B_off, B_rec, nullptr, B_hp16, B_ls, B_ld,
                                                   bias0, g0, be0, B_h, B_h16,
                                                   nullptr, nullptr, nullptr, nullptr);

    // layer 1 (agg + LN + fused layer-2 ls/ld)
    k_proj_attn_mfma<<<PB, 256, 0, stream>>>(B_h16, B_w1bf, as1, ad1, B_hp16, B_ls, B_ld);
    k_agg32<false><<<N_NODES / 4, 256, 0, stream>>>(B_off, nullptr, B_csrc, B_hp16, B_ls, B_ld,
                                                    bias1, g1, be1, B_h, B_h16,
                                                    B_us, B_ud, B_ls2, B_ld2);

    // layer 2: aggregate inputs, then fused {W2-proj + LN + W_out-proj} via MFMA
    k_agg2<<<N_NODES / 4, 256, 0, stream>>>(B_off, B_csrc, B_h16, B_ls2, B_ld2, B_aggq);
    k_gemm_post<<<(N_NODES + 63) / 64, 256, 0, stream>>>(B_aggq, B_w2bf, bias2, g2, be2,
                                                         B_h, B_woutbf, b_out, out);
}

// Round 14
// 539.706 us; speedup vs baseline: 1.1437x; 1.0243x over previous
//
#include <hip/hip_runtime.h>
#include <hip/hip_bf16.h>
#include <math.h>

#define N_NODES 50000
#define N_EDGES 1600000
#define N_TOT   (N_EDGES + N_NODES)
#define NBKT 64

typedef unsigned short ushort_t;
typedef short short8v __attribute__((ext_vector_type(8)));
typedef float f32x4 __attribute__((ext_vector_type(4)));
typedef float f32x4v __attribute__((ext_vector_type(4)));
typedef int   i32x4v __attribute__((ext_vector_type(4)));

__device__ __forceinline__ float lrelu(float x) { return x > 0.f ? x : 0.2f * x; }
__device__ __forceinline__ float bf2f(ushort_t u) { return __uint_as_float((unsigned)u << 16); }
__device__ __forceinline__ ushort_t f2bf(float f) {
    union { __hip_bfloat16 b; ushort_t u; } cv;
    cv.b = __float2bfloat16(f);
    return cv.u;
}

// ---------------- CSR build ----------------
__global__ void k_count(const int* __restrict__ ei, int* __restrict__ cnt) {
    int e = blockIdx.x * 256 + threadIdx.x;
    if (e >= N_TOT) return;
    int dst = (e < N_EDGES) ? ei[N_EDGES + e] : (e - N_EDGES);
    atomicAdd(&cnt[dst], 1);
}

__global__ void k_scan1(const int* __restrict__ cnt, int* __restrict__ bsum) {
    __shared__ int ws[4];
    int g = blockIdx.x * 256 + threadIdx.x;
    int lane = threadIdx.x & 63, wv = threadIdx.x >> 6;
    int x = (g < N_NODES) ? cnt[g] : 0;
#pragma unroll
    for (int s = 1; s < 64; s <<= 1) x += __shfl_xor(x, s, 64);
    if (lane == 0) ws[wv] = x;
    __syncthreads();
    if (threadIdx.x == 0) bsum[blockIdx.x] = ws[0] + ws[1] + ws[2] + ws[3];
}

__global__ void k_scan2(const int* __restrict__ bsum, int* __restrict__ boff) {
    __shared__ int ws[4];
    const int NB = (N_NODES + 255) / 256;
    int t = threadIdx.x, lane = t & 63, wv = t >> 6;
    int v = (t < NB) ? bsum[t] : 0;
    int x = v;
#pragma unroll
    for (int s = 1; s < 64; s <<= 1) { int tt = __shfl_up(x, s, 64); if (lane >= s) x += tt; }
    if (lane == 63) ws[wv] = x;
    __syncthreads();
    int add = 0;
#pragma unroll
    for (int w = 0; w < 4; ++w) add += (w < wv) ? ws[w] : 0;
    x += add;
    if (t < NB) boff[t] = x - v;   // exclusive
}

__global__ void k_scan3(const int* __restrict__ cnt, const int* __restrict__ boff,
                        int* __restrict__ off) {
    __shared__ int ws[4];
    int g = blockIdx.x * 256 + threadIdx.x;
    int lane = threadIdx.x & 63, wv = threadIdx.x >> 6;
    int v = (g < N_NODES) ? cnt[g] : 0;
    int x = v;
#pragma unroll
    for (int s = 1; s < 64; s <<= 1) { int tt = __shfl_up(x, s, 64); if (lane >= s) x += tt; }
    if (lane == 63) ws[wv] = x;
    __syncthreads();
    int add = 0;
#pragma unroll
    for (int w = 0; w < 4; ++w) add += (w < wv) ? ws[w] : 0;
    x += add;
    if (g < N_NODES) off[g + 1] = boff[blockIdx.x] + x;
    if (g == 0) off[0] = 0;
}

// self-loop records: {n, aloop packed}
__global__ void k_fill_loop(const int* __restrict__ off, int* __restrict__ cur,
                            const float* __restrict__ aloop, int* __restrict__ rec) {
    int n = blockIdx.x * 256 + threadIdx.x;
    if (n >= N_NODES) return;
    unsigned ax = (unsigned)f2bf(aloop[0]) | ((unsigned)f2bf(aloop[1]) << 16);
    unsigned ay = (unsigned)f2bf(aloop[2]) | ((unsigned)f2bf(aloop[3]) << 16);
    int pos = off[n] + atomicAdd(&cur[n], 1);
    i32x4v r = {n, (int)ax, (int)ay, 0};
    __builtin_nontemporal_store(r, (i32x4v*)(rec + (size_t)pos * 4));
}

// ---------------- edge attention precompute ----------------
__global__ void k_v(const float* __restrict__ We0, const float* __restrict__ ae0,
                    float* __restrict__ v) {
    int t = threadIdx.x;            // 0..127
    int h = t >> 5, k = t & 31;
    float s = 0.f;
    for (int c = 0; c < 32; ++c) s += We0[k * 128 + h * 32 + c] * ae0[h * 32 + c];
    v[h * 32 + k] = s;
}

// epW (32x32 row-major) -> bf16 MFMA fragments (used as A = epW^T tiles)
__global__ void k_wepbf(const float* __restrict__ epW, ushort_t* __restrict__ Bp) {
    int t = threadIdx.x;              // 0..127
    if (t >= 128) return;
    int lane = t & 63, ct = t >> 6;
    int j = ct * 16 + (lane & 15);
    int kbase = (lane >> 4) * 8;
    ushort_t o[8];
#pragma unroll
    for (int jj = 0; jj < 8; ++jj) o[jj] = f2bf(epW[(kbase + jj) * 32 + j]);
    ((uint4*)Bp)[t] = *(uint4*)o;
}

// MFMA edge-attention (transposed) + fused CSR scatter; nt loads/stores; bucketed easum.
__global__ void k_alpha_mfma(const float* __restrict__ eattr, const ushort_t* __restrict__ Aw,
                             const float* __restrict__ epb, const float* __restrict__ v,
                             const int* __restrict__ ei, const int* __restrict__ off,
                             int* __restrict__ cur, int* __restrict__ rec,
                             float* __restrict__ easum_part) {
    __shared__ float sums[4][32];
    int tid = threadIdx.x;
    int lane = tid & 63, wv = tid >> 6;
    int c = lane & 15, g = lane >> 4;   // c = edge column, g = channel group
    int e0base = blockIdx.x * 256 + wv * 64;

    // hoisted: CSR slot reservation
    int e = e0base + lane;
    int src = __builtin_nontemporal_load(&ei[e]);
    int dst = __builtin_nontemporal_load(&ei[N_EDGES + e]);
    int pos = off[dst] + atomicAdd(&cur[dst], 1);

    // hoisted: stage all eattr tiles (streaming, don't pollute L2)
    f32x4v F0[4], F1[4];
#pragma unroll
    for (int t = 0; t < 4; ++t) {
        const f32x4v* ap = (const f32x4v*)(eattr + (size_t)(e0base + t * 16 + c) * 32 + g * 8);
        F0[t] = __builtin_nontemporal_load(ap);
        F1[t] = __builtin_nontemporal_load(ap + 1);
    }

    short8v a0 = ((const short8v*)Aw)[lane];        // channels 0-15
    short8v a1 = ((const short8v*)Aw)[64 + lane];   // channels 16-31

    float eb0[4], eb1[4], vv0[4][4], vv1[4][4];
#pragma unroll
    for (int r = 0; r < 4; ++r) {
        eb0[r] = epb[g * 4 + r];
        eb1[r] = epb[16 + g * 4 + r];
#pragma unroll
        for (int h = 0; h < 4; ++h) {
            vv0[h][r] = v[h * 32 + g * 4 + r];
            vv1[h][r] = v[h * 32 + 16 + g * 4 + r];
        }
    }

    float se0[4] = {0.f, 0.f, 0.f, 0.f}, se1[4] = {0.f, 0.f, 0.f, 0.f};
    uint2 oo0, oo1, oo2, oo3;
#pragma unroll
    for (int t = 0; t < 4; ++t) {
        f32x4v f0 = F0[t], f1 = F1[t];
        ushort_t ai[8];
        ai[0] = f2bf(f0.x); ai[1] = f2bf(f0.y); ai[2] = f2bf(f0.z); ai[3] = f2bf(f0.w);
        ai[4] = f2bf(f1.x); ai[5] = f2bf(f1.y); ai[6] = f2bf(f1.z); ai[7] = f2bf(f1.w);
        short8v b = *(short8v*)ai;                  // B = eattr^T fragment
        f32x4 acc0 = (f32x4){0.f, 0.f, 0.f, 0.f};
        f32x4 acc1 = (f32x4){0.f, 0.f, 0.f, 0.f};
        acc0 = __builtin_amdgcn_mfma_f32_16x16x32_bf16(a0, b, acc0, 0, 0, 0);
        acc1 = __builtin_amdgcn_mfma_f32_16x16x32_bf16(a1, b, acc1, 0, 0, 0);
        float p0 = 0.f, p1 = 0.f, p2 = 0.f, p3 = 0.f;
#pragma unroll
        for (int r = 0; r < 4; ++r) {
            float u0 = fmaxf(acc0[r] + eb0[r], 0.f);
            float u1 = fmaxf(acc1[r] + eb1[r], 0.f);
            se0[r] += u0; se1[r] += u1;
            p0 += u0 * vv0[0][r] + u1 * vv1[0][r];
            p1 += u0 * vv0[1][r] + u1 * vv1[1][r];
            p2 += u0 * vv0[2][r] + u1 * vv1[2][r];
            p3 += u0 * vv0[3][r] + u1 * vv1[3][r];
        }
        p0 += __shfl_xor(p0, 16, 64); p0 += __shfl_xor(p0, 32, 64);
        p1 += __shfl_xor(p1, 16, 64); p1 += __shfl_xor(p1, 32, 64);
        p2 += __shfl_xor(p2, 16, 64); p2 += __shfl_xor(p2, 32, 64);
        p3 += __shfl_xor(p3, 16, 64); p3 += __shfl_xor(p3, 32, 64);
        uint2 o;
        o.x = (unsigned)f2bf(p0) | ((unsigned)f2bf(p1) << 16);
        o.y = (unsigned)f2bf(p2) | ((unsigned)f2bf(p3) << 16);
        if (t == 0) oo0 = o; else if (t == 1) oo1 = o; else if (t == 2) oo2 = o; else oo3 = o;
    }
    uint2 o = oo0;
    o.x = (g == 1) ? oo1.x : o.x; o.y = (g == 1) ? oo1.y : o.y;
    o.x = (g == 2) ? oo2.x : o.x; o.y = (g == 2) ? oo2.y : o.y;
    o.x = (g == 3) ? oo3.x : o.x; o.y = (g == 3) ? oo3.y : o.y;
    i32x4v rv = {src, (int)o.x, (int)o.y, 0};
    __builtin_nontemporal_store(rv, (i32x4v*)(rec + (size_t)pos * 4));

    // easum partials (64-way bucketed)
#pragma unroll
    for (int r = 0; r < 4; ++r) {
#pragma unroll
        for (int m = 1; m < 16; m <<= 1) {
            se0[r] += __shfl_xor(se0[r], m, 64);
            se1[r] += __shfl_xor(se1[r], m, 64);
        }
    }
    if (c == 0) {
#pragma unroll
        for (int r = 0; r < 4; ++r) {
            sums[wv][g * 4 + r] = se0[r];
            sums[wv][16 + g * 4 + r] = se1[r];
        }
    }
    __syncthreads();
    if (tid < 32) {
        atomicAdd(&easum_part[(blockIdx.x & (NBKT - 1)) * 32 + tid],
                  sums[0][tid] + sums[1][tid] + sums[2][tid] + sums[3][tid]);
    }
}

// reduce easum buckets, then aloop[h] = mean(ea) . v[h]
__global__ void k_aloop(const float* __restrict__ easum_part, const float* __restrict__ v,
                        float* __restrict__ aloop) {
    __shared__ float es[32];
    int t = threadIdx.x;
    if (t < 32) {
        float s = 0.f;
        for (int b = 0; b < NBKT; ++b) s += easum_part[b * 32 + t];
        es[t] = s;
    }
    __syncthreads();
    if (t < 4) {
        float s = 0.f;
        for (int c = 0; c < 32; ++c) s += (es[c] * (1.f / (float)N_EDGES)) * v[t * 32 + c];
        aloop[t] = s;
    }
}

// ---------------- weight conversion: 128x128 f32 -> MFMA B-fragment bf16 ----------------
__global__ void k_wbf(const float* __restrict__ W, ushort_t* __restrict__ Bp) {
    int t = blockIdx.x * 256 + threadIdx.x;   // 0..2047
    if (t >= 2048) return;
    int lane = t & 63;
    int ct = (t >> 6) & 7;
    int kb = t >> 9;
    int j = ct * 16 + (lane & 15);
    int kbase = kb * 32 + (lane >> 4) * 8;
    ushort_t o[8];
#pragma unroll
    for (int jj = 0; jj < 8; ++jj) o[jj] = f2bf(W[(kbase + jj) * 128 + j]);
    ((uint4*)Bp)[t] = *(uint4*)o;
}

// W2 (512x128 effective) -> B-fragments
__global__ void k_w2bf(const float* __restrict__ W2, ushort_t* __restrict__ Bp) {
    int t = blockIdx.x * 256 + threadIdx.x;   // 0..8191
    if (t >= 8192) return;
    int lane = t & 63;
    int ct = (t >> 6) & 7;
    int kb = t >> 9;
    int j = ct * 16 + (lane & 15);
    int kbase = kb * 32 + (lane >> 4) * 8;
    ushort_t o[8];
#pragma unroll
    for (int jj = 0; jj < 8; ++jj) {
        int kk = kbase + jj;
        int h = kk >> 7, kp = kk & 127;
        o[jj] = f2bf(W2[kp * 512 + h * 128 + j]);
    }
    ((uint4*)Bp)[t] = *(uint4*)o;
}

// ---------------- GEMMs ----------------
__global__ void k_proj_in(const float* __restrict__ x, const float* __restrict__ W,
                          const float* __restrict__ b, float* __restrict__ h,
                          ushort_t* __restrict__ h16) {
    int j = threadIdx.x;               // 0..127
    int n0 = blockIdx.x * 4;
    const float* x0 = x + (size_t)n0 * 64;
    float a0 = 0.f, a1 = 0.f, a2 = 0.f, a3 = 0.f;
    for (int k = 0; k < 64; ++k) {
        float w = W[k * 128 + j];
        a0 += x0[k] * w;
        a1 += x0[64 + k] * w;
        a2 += x0[128 + k] * w;
        a3 += x0[192 + k] * w;
    }
    float bb = b[j];
    a0 = fmaxf(a0 + bb, 0.f); a1 = fmaxf(a1 + bb, 0.f);
    a2 = fmaxf(a2 + bb, 0.f); a3 = fmaxf(a3 + bb, 0.f);
    h[(size_t)(n0 + 0) * 128 + j] = a0;
    h[(size_t)(n0 + 1) * 128 + j] = a1;
    h[(size_t)(n0 + 2) * 128 + j] = a2;
    h[(size_t)(n0 + 3) * 128 + j] = a3;
    h16[(size_t)(n0 + 0) * 128 + j] = f2bf(a0);
    h16[(size_t)(n0 + 1) * 128 + j] = f2bf(a1);
    h16[(size_t)(n0 + 2) * 128 + j] = f2bf(a2);
    h16[(size_t)(n0 + 3) * 128 + j] = f2bf(a3);
}

// MFMA projection: hp16 = bf16(h16 @ Wbf); fused ls/ld
__global__ void k_proj_attn_mfma(const ushort_t* __restrict__ h16, const ushort_t* __restrict__ Bp,
                                 const float* __restrict__ as_, const float* __restrict__ ad_,
                                 ushort_t* __restrict__ hp16, float* __restrict__ ls,
                                 float* __restrict__ ld) {
    int tid = threadIdx.x;
    int lane = tid & 63, wid = tid >> 6;
    int n0 = blockIdx.x * 64 + wid * 16;
    int arow = n0 + (lane & 15);
    int arc = arow < N_NODES ? arow : 0;
    int koff = (lane >> 4) * 8;
    const short8v* ap = (const short8v*)(h16 + (size_t)arc * 128 + koff);
    const short8v* bp = (const short8v*)Bp;

    f32x4 acc[8];
#pragma unroll
    for (int ct = 0; ct < 8; ++ct) acc[ct] = (f32x4){0.f, 0.f, 0.f, 0.f};
#pragma unroll
    for (int kb = 0; kb < 4; ++kb) {
        short8v a = ap[kb * 4];
#pragma unroll
        for (int ct = 0; ct < 8; ++ct) {
            short8v b = bp[(kb * 8 + ct) * 64 + lane];
            acc[ct] = __builtin_amdgcn_mfma_f32_16x16x32_bf16(a, b, acc[ct], 0, 0, 0);
        }
    }

    int q = lane >> 4, c = lane & 15;
#pragma unroll
    for (int reg = 0; reg < 4; ++reg) {
        int row = n0 + q * 4 + reg;
        if (row < N_NODES) {
#pragma unroll
            for (int ct = 0; ct < 8; ++ct)
                hp16[(size_t)row * 128 + ct * 16 + c] = f2bf(acc[ct][reg]);
        }
    }
#pragma unroll
    for (int h = 0; h < 4; ++h) {
        float alo = as_[h * 32 + c], ahi = as_[h * 32 + 16 + c];
        float dlo = ad_[h * 32 + c], dhi = ad_[h * 32 + 16 + c];
#pragma unroll
        for (int reg = 0; reg < 4; ++reg) {
            float s = acc[2 * h][reg] * alo + acc[2 * h + 1][reg] * ahi;
            float d = acc[2 * h][reg] * dlo + acc[2 * h + 1][reg] * dhi;
#pragma unroll
            for (int m = 1; m < 16; m <<= 1) {
                s += __shfl_xor(s, m, 64);
                d += __shfl_xor(d, m, 64);
            }
            int row = n0 + q * 4 + reg;
            if (c == 0 && row < N_NODES) {
                ls[row * 4 + h] = s;
                ld[row * 4 + h] = d;
            }
        }
    }
}

// u_s[h,k] = sum_c W2[k, h*128+c] * as2[h,c] (and u_d)
__global__ void k_u(const float* __restrict__ W2, const float* __restrict__ as2,
                    const float* __restrict__ ad2, float* __restrict__ us,
                    float* __restrict__ ud) {
    int t = blockIdx.x * 256 + threadIdx.x;
    if (t >= 512) return;
    int h = t >> 7, k = t & 127;
    float ss = 0.f, dd = 0.f;
    for (int c = 0; c < 128; ++c) {
        float w = W2[k * 512 + h * 128 + c];
        ss += w * as2[h * 128 + c];
        dd += w * ad2[h * 128 + c];
    }
    us[h * 128 + k] = ss;
    ud[h * 128 + k] = dd;
}

// ---- GAT aggregation + fused residual/LayerNorm (+ csrc emit / ls2,ld2), 4 nodes/block --
template <bool L0>
__global__ void k_agg32(const int* __restrict__ off, const int4* __restrict__ rec,
                        int* __restrict__ csrc,
                        const ushort_t* __restrict__ hp16, const float* __restrict__ ls,
                        const float* __restrict__ ld,
                        const float* __restrict__ bias, const float* __restrict__ g,
                        const float* __restrict__ be,
                        float* h, ushort_t* __restrict__ h16,
                        const float* __restrict__ us, const float* __restrict__ ud,
                        float* __restrict__ ls2, float* __restrict__ ld2) {
    __shared__ float swt[4][64][4];
    __shared__ int ssrc[4][64];
    int wv = threadIdx.x >> 6, lane = threadIdx.x & 63;
    int n = blockIdx.x * 4 + wv;
    int beg = off[n], deg = off[n + 1] - beg;
    float4 ldv = *(const float4*)(ld + n * 4);

    int hsel = lane >> 4;   // head of channels {2*lane, 2*lane+1}
    float acc0 = 0.f, acc1 = 0.f;
    float d0 = 0.f, d1 = 0.f, d2 = 0.f, d3 = 0.f;
    for (int base = 0; base < deg; base += 64) {
        int i = base + lane;
        float w0 = 0, w1 = 0, w2 = 0, w3 = 0;
        int s = 0;
        if (i < deg) {
            float a0 = 0, a1 = 0, a2 = 0, a3 = 0;
            if (L0) {
                int4 r = rec[beg + i];
                s = r.x;
                csrc[beg + i] = s;   // fused extract for layers 1/2
                a0 = bf2f((ushort_t)((unsigned)r.y & 0xffffu));
                a1 = bf2f((ushort_t)((unsigned)r.y >> 16));
                a2 = bf2f((ushort_t)((unsigned)r.z & 0xffffu));
                a3 = bf2f((ushort_t)((unsigned)r.z >> 16));
            } else {
                s = csrc[beg + i];
            }
            float4 lsv = *(const float4*)(ls + s * 4);
            w0 = __expf(lrelu(lsv.x + ldv.x + a0)); d0 += w0;
            w1 = __expf(lrelu(lsv.y + ldv.y + a1)); d1 += w1;
            w2 = __expf(lrelu(lsv.z + ldv.z + a2)); d2 += w2;
            w3 = __expf(lrelu(lsv.w + ldv.w + a3)); d3 += w3;
        }
        *(float4*)&swt[wv][lane][0] = make_float4(w0, w1, w2, w3);
        ssrc[wv][lane] = s;
        int cnt = min(64, deg - base);
        int jj = 0;
        for (; jj + 4 <= cnt; jj += 4) {
            float wA = swt[wv][jj + 0][hsel]; int sA = ssrc[wv][jj + 0];
            float wB = swt[wv][jj + 1][hsel]; int sB = ssrc[wv][jj + 1];
            float wC = swt[wv][jj + 2][hsel]; int sC = ssrc[wv][jj + 2];
            float wD = swt[wv][jj + 3][hsel]; int sD = ssrc[wv][jj + 3];
            ushort2 vA = ((const ushort2*)(hp16 + (size_t)sA * 128))[lane];
            ushort2 vB = ((const ushort2*)(hp16 + (size_t)sB * 128))[lane];
            ushort2 vC = ((const ushort2*)(hp16 + (size_t)sC * 128))[lane];
            ushort2 vD = ((const ushort2*)(hp16 + (size_t)sD * 128))[lane];
            acc0 += bf2f(vA.x) * wA; acc1 += bf2f(vA.y) * wA;
            acc0 += bf2f(vB.x) * wB; acc1 += bf2f(vB.y) * wB;
            acc0 += bf2f(vC.x) * wC; acc1 += bf2f(vC.y) * wC;
            acc0 += bf2f(vD.x) * wD; acc1 += bf2f(vD.y) * wD;
        }
        for (; jj < cnt; ++jj) {
            float wA = swt[wv][jj][hsel];
            int sA = ssrc[wv][jj];
            ushort2 vA = ((const ushort2*)(hp16 + (size_t)sA * 128))[lane];
            acc0 += bf2f(vA.x) * wA;
            acc1 += bf2f(vA.y) * wA;
        }
    }
#pragma unroll
    for (int k = 1; k < 64; k <<= 1) {
        d0 += __shfl_xor(d0, k, 64); d1 += __shfl_xor(d1, k, 64);
        d2 += __shfl_xor(d2, k, 64); d3 += __shfl_xor(d3, k, 64);
    }
    float dsel = (hsel == 0) ? d0 : (hsel == 1) ? d1 : (hsel == 2) ? d2 : d3;
    float2 bb = ((const float2*)bias)[lane];
    size_t hbase = (size_t)n * 128;
    float2 hres = ((const float2*)(h + hbase))[lane];
    float v0 = acc0 / dsel + bb.x + hres.x;
    float v1 = acc1 / dsel + bb.y + hres.y;
    float s = v0 + v1, ss = v0 * v0 + v1 * v1;
#pragma unroll
    for (int k = 1; k < 64; k <<= 1) { s += __shfl_xor(s, k, 64); ss += __shfl_xor(ss, k, 64); }
    float mean = s * (1.f / 128.f);
    float var = ss * (1.f / 128.f) - mean * mean;
    float inv = rsqrtf(var + 1e-5f);
    float2 gg = ((const float2*)g)[lane];
    float2 bee = ((const float2*)be)[lane];
    float r0 = (v0 - mean) * inv * gg.x + bee.x;
    float r1 = (v1 - mean) * inv * gg.y + bee.y;
    ((float2*)(h + hbase))[lane] = make_float2(r0, r1);
    ushort2 o16; o16.x = f2bf(r0); o16.y = f2bf(r1);
    ((ushort2*)(h16 + hbase))[lane] = o16;

    if (!L0) {
        float sh[4], dh[4];
#pragma unroll
        for (int hh = 0; hh < 4; ++hh) {
            float2 u2 = ((const float2*)(us + hh * 128))[lane];
            float2 w2 = ((const float2*)(ud + hh * 128))[lane];
            sh[hh] = r0 * u2.x + r1 * u2.y;
            dh[hh] = r0 * w2.x + r1 * w2.y;
        }
#pragma unroll
        for (int k = 1; k < 64; k <<= 1) {
#pragma unroll
            for (int hh = 0; hh < 4; ++hh) {
                sh[hh] += __shfl_xor(sh[hh], k, 64);
                dh[hh] += __shfl_xor(dh[hh], k, 64);
            }
        }
        if (lane == 0) {
#pragma unroll
            for (int hh = 0; hh < 4; ++hh) {
                ls2[n * 4 + hh] = sh[hh];
                ld2[n * 4 + hh] = dh[hh];
            }
        }
    }
}

// ---------- layer-2 aggregation: single-pass, gather INPUT h (bf16), 4 nodes/block --
__global__ void k_agg2(const int* __restrict__ off, const int* __restrict__ csrc,
                       const ushort_t* __restrict__ h16, const float* __restrict__ ls,
                       const float* __restrict__ ld, ushort_t* __restrict__ aggq) {
    __shared__ float4 swt[4][64];
    __shared__ int ssrc[4][64];
    int wv = threadIdx.x >> 6, lane = threadIdx.x & 63;
    int n = blockIdx.x * 4 + wv;
    int beg = off[n], deg = off[n + 1] - beg;
    float4 ldv = *(const float4*)(ld + n * 4);

    float a00 = 0, a01 = 0, a10 = 0, a11 = 0, a20 = 0, a21 = 0, a30 = 0, a31 = 0;
    float d0 = 0, d1 = 0, d2 = 0, d3 = 0;
    for (int base = 0; base < deg; base += 64) {
        int i = base + lane;
        float w0 = 0, w1 = 0, w2 = 0, w3 = 0;
        int s = 0;
        if (i < deg) {
            s = csrc[beg + i];
            float4 lsv = *(const float4*)(ls + s * 4);
            w0 = __expf(lrelu(lsv.x + ldv.x)); d0 += w0;
            w1 = __expf(lrelu(lsv.y + ldv.y)); d1 += w1;
            w2 = __expf(lrelu(lsv.z + ldv.z)); d2 += w2;
            w3 = __expf(lrelu(lsv.w + ldv.w)); d3 += w3;
        }
        swt[wv][lane] = make_float4(w0, w1, w2, w3);
        ssrc[wv][lane] = s;
        int cnt = min(64, deg - base);
        int jj = 0;
        for (; jj + 2 <= cnt; jj += 2) {
            float4 wA = swt[wv][jj];     int sA = ssrc[wv][jj];
            float4 wB = swt[wv][jj + 1]; int sB = ssrc[wv][jj + 1];
            ushort2 vA = ((const ushort2*)(h16 + (size_t)sA * 128))[lane];
            ushort2 vB = ((const ushort2*)(h16 + (size_t)sB * 128))[lane];
            float fA0 = bf2f(vA.x), fA1 = bf2f(vA.y);
            float fB0 = bf2f(vB.x), fB1 = bf2f(vB.y);
            a00 += fA0 * wA.x; a01 += fA1 * wA.x;
            a10 += fA0 * wA.y; a11 += fA1 * wA.y;
            a20 += fA0 * wA.z; a21 += fA1 * wA.z;
            a30 += fA0 * wA.w; a31 += fA1 * wA.w;
            a00 += fB0 * wB.x; a01 += fB1 * wB.x;
            a10 += fB0 * wB.y; a11 += fB1 * wB.y;
            a20 += fB0 * wB.z; a21 += fB1 * wB.z;
            a30 += fB0 * wB.w; a31 += fB1 * wB.w;
        }
        for (; jj < cnt; ++jj) {
            float4 w4 = swt[wv][jj];
            int sj = ssrc[wv][jj];
            ushort2 v = ((const ushort2*)(h16 + (size_t)sj * 128))[lane];
            float f0 = bf2f(v.x), f1 = bf2f(v.y);
            a00 += f0 * w4.x; a01 += f1 * w4.x;
            a10 += f0 * w4.y; a11 += f1 * w4.y;
            a20 += f0 * w4.z; a21 += f1 * w4.z;
            a30 += f0 * w4.w; a31 += f1 * w4.w;
        }
    }
#pragma unroll
    for (int k = 1; k < 64; k <<= 1) {
        d0 += __shfl_xor(d0, k, 64); d1 += __shfl_xor(d1, k, 64);
        d2 += __shfl_xor(d2, k, 64); d3 += __shfl_xor(d3, k, 64);
    }
    float r0 = 0.25f / d0, r1 = 0.25f / d1, r2 = 0.25f / d2, r3 = 0.25f / d3;
    ushort_t* base_p = aggq + (size_t)n * 512;
    ushort2 w;
    w.x = f2bf(a00 * r0); w.y = f2bf(a01 * r0); ((ushort2*)(base_p      ))[lane] = w;
    w.x = f2bf(a10 * r1); w.y = f2bf(a11 * r1); ((ushort2*)(base_p + 128))[lane] = w;
    w.x = f2bf(a20 * r2); w.y = f2bf(a21 * r2); ((ushort2*)(base_p + 256))[lane] = w;
    w.x = f2bf(a30 * r3); w.y = f2bf(a31 * r3); ((ushort2*)(base_p + 384))[lane] = w;
}

// --- MFMA GEMM: t = LN(aggq @ W2bf + bias2 + hbuf); out = t @ W_out + b_out (fused) ---
__global__ void k_gemm_post(const ushort_t* __restrict__ aggq, const ushort_t* __restrict__ Bp,
                            const float* __restrict__ bias, const float* __restrict__ g,
                            const float* __restrict__ be, const float* __restrict__ hbuf,
                            const ushort_t* __restrict__ Wout_bp, const float* __restrict__ b_out,
                            float* __restrict__ out) {
    __shared__ ushort_t tile[4][16][136];   // per-wave 16x128 bf16, padded
    int tid = threadIdx.x;
    int lane = tid & 63, wid = tid >> 6;
    int n0 = blockIdx.x * 64 + wid * 16;
    int arow = n0 + (lane & 15);
    int arc = arow < N_NODES ? arow : 0;
    int koff = (lane >> 4) * 8;

    const short8v* ap = (const short8v*)(aggq + (size_t)arc * 512 + koff);
    const short8v* bp = (const short8v*)Bp;

    f32x4 acc[8];
#pragma unroll
    for (int ct = 0; ct < 8; ++ct) acc[ct] = (f32x4){0.f, 0.f, 0.f, 0.f};
#pragma unroll
    for (int kb = 0; kb < 16; ++kb) {
        short8v a = ap[kb * 4];
#pragma unroll
        for (int ct = 0; ct < 8; ++ct) {
            short8v b = bp[(kb * 8 + ct) * 64 + lane];
            acc[ct] = __builtin_amdgcn_mfma_f32_16x16x32_bf16(a, b, acc[ct], 0, 0, 0);
        }
    }

    int q = lane >> 4, c = lane & 15;
    float gv[8], bev[8], bv[8];
#pragma unroll
    for (int ct = 0; ct < 8; ++ct) {
        int col = ct * 16 + c;
        gv[ct] = g[col]; bev[ct] = be[col]; bv[ct] = bias[col];
    }
#pragma unroll
    for (int reg = 0; reg < 4; ++reg) {
        int row = n0 + q * 4 + reg;
        int rc = row < N_NODES ? row : 0;
        float v[8];
        float s = 0.f, ss = 0.f;
#pragma unroll
        for (int ct = 0; ct < 8; ++ct) {
            float val = acc[ct][reg] + bv[ct] + hbuf[(size_t)rc * 128 + ct * 16 + c];
            v[ct] = val; s += val; ss += val * val;
        }
#pragma unroll
        for (int m = 1; m < 16; m <<= 1) {
            s += __shfl_xor(s, m, 64);
            ss += __shfl_xor(ss, m, 64);
        }
        float mean = s * (1.f / 128.f);
        float var = ss * (1.f / 128.f) - mean * mean;
        float inv = rsqrtf(var + 1e-5f);
        int lrow = q * 4 + reg;
#pragma unroll
        for (int ct = 0; ct < 8; ++ct)
            tile[wid][lrow][ct * 16 + c] = f2bf((v[ct] - mean) * inv * gv[ct] + bev[ct]);
    }

    const short8v* wp = (const short8v*)Wout_bp;
    f32x4 acc2[8];
#pragma unroll
    for (int ct = 0; ct < 8; ++ct) acc2[ct] = (f32x4){0.f, 0.f, 0.f, 0.f};
#pragma unroll
    for (int kb = 0; kb < 4; ++kb) {
        short8v a = *(const short8v*)&tile[wid][lane & 15][kb * 32 + koff];
#pragma unroll
        for (int ct = 0; ct < 8; ++ct) {
            short8v b = wp[(kb * 8 + ct) * 64 + lane];
            acc2[ct] = __builtin_amdgcn_mfma_f32_16x16x32_bf16(a, b, acc2[ct], 0, 0, 0);
        }
    }
    float bo[8];
#pragma unroll
    for (int ct = 0; ct < 8; ++ct) bo[ct] = b_out[ct * 16 + c];
#pragma unroll
    for (int reg = 0; reg < 4; ++reg) {
        int row = n0 + q * 4 + reg;
        if (row < N_NODES) {
#pragma unroll
            for (int ct = 0; ct < 8; ++ct)
                out[(size_t)row * 128 + ct * 16 + c] = acc2[ct][reg] + bo[ct];
        }
    }
}

extern "C" void kernel_launch(void* const* d_in, const int* in_sizes, int n_in,
                              void* d_out, int out_size, void* d_ws, size_t ws_size,
                              hipStream_t stream) {
    const float* x     = (const float*)d_in[0];
    const int*   ei    = (const int*)d_in[1];
    const float* eattr = (const float*)d_in[2];
    const float* W_in  = (const float*)d_in[3];
    const float* b_in  = (const float*)d_in[4];
    const float* epW   = (const float*)d_in[5];
    const float* epb   = (const float*)d_in[6];
    const float* W0    = (const float*)d_in[7];
    const float* as0   = (const float*)d_in[8];
    const float* ad0   = (const float*)d_in[9];
    const float* We0   = (const float*)d_in[10];
    const float* ae0   = (const float*)d_in[11];
    const float* bias0 = (const float*)d_in[12];
    const float* g0    = (const float*)d_in[13];
    const float* be0   = (const float*)d_in[14];
    const float* W1    = (const float*)d_in[15];
    const float* as1   = (const float*)d_in[16];
    const float* ad1   = (const float*)d_in[17];
    const float* bias1 = (const float*)d_in[18];
    const float* g1    = (const float*)d_in[19];
    const float* be1   = (const float*)d_in[20];
    const float* W2    = (const float*)d_in[21];
    const float* as2   = (const float*)d_in[22];
    const float* ad2   = (const float*)d_in[23];
    const float* bias2 = (const float*)d_in[24];
    const float* g2    = (const float*)d_in[25];
    const float* be2   = (const float*)d_in[26];
    const float* W_out = (const float*)d_in[27];
    const float* b_out = (const float*)d_in[28];
    float* out = (float*)d_out;

    char* wp = (char*)d_ws;
    auto alloc = [&](size_t bytes) {
        char* p = wp;
        wp += (bytes + 255) & ~(size_t)255;
        return p;
    };
    float*    B_h    = (float*)alloc((size_t)N_NODES * 128 * 4);
    ushort_t* B_hp16 = (ushort_t*)alloc((size_t)N_NODES * 128 * 2);
    ushort_t* B_h16  = (ushort_t*)alloc((size_t)N_NODES * 128 * 2);
    // union: rec (N_TOT*16B) dies before aggq (N*512*2B) is written
    char*     B_u    = (char*)alloc(52800000);
    int*      B_rec  = (int*)B_u;
    ushort_t* B_aggq = (ushort_t*)B_u;
    float* B_ls  = (float*)alloc((size_t)N_NODES * 4 * 4);
    float* B_ld  = (float*)alloc((size_t)N_NODES * 4 * 4);
    float* B_ls2 = (float*)alloc((size_t)N_NODES * 4 * 4);
    float* B_ld2 = (float*)alloc((size_t)N_NODES * 4 * 4);
    int*   B_off = (int*)alloc((size_t)(N_NODES + 1) * 4);
    int*   B_cnt = (int*)alloc((size_t)N_NODES * 4);
    int*   B_cur = (int*)alloc((size_t)N_NODES * 4);
    int*   B_csrc = (int*)alloc((size_t)N_TOT * 4);
    int*   B_bsum = (int*)alloc(256 * 4);
    int*   B_boff = (int*)alloc(256 * 4);
    float* B_v    = (float*)alloc(128 * 4);
    float* B_easum_part = (float*)alloc(NBKT * 32 * 4);
    float* B_aloop = (float*)alloc(4 * 4);
    float* B_us   = (float*)alloc(512 * 4);
    float* B_ud   = (float*)alloc(512 * 4);
    ushort_t* B_w2bf   = (ushort_t*)alloc(8192 * 16);
    ushort_t* B_w0bf   = (ushort_t*)alloc(2048 * 16);
    ushort_t* B_w1bf   = (ushort_t*)alloc(2048 * 16);
    ushort_t* B_woutbf = (ushort_t*)alloc(2048 * 16);
    ushort_t* B_wepbf  = (ushort_t*)alloc(128 * 16);

    hipMemsetAsync(B_cnt, 0, (size_t)N_NODES * 4, stream);
    hipMemsetAsync(B_cur, 0, (size_t)N_NODES * 4, stream);
    hipMemsetAsync(B_easum_part, 0, NBKT * 32 * 4, stream);

    const int NB = (N_NODES + 255) / 256;
    int eblocks = (N_TOT + 255) / 256;
    k_count<<<eblocks, 256, 0, stream>>>(ei, B_cnt);
    k_scan1<<<NB, 256, 0, stream>>>(B_cnt, B_bsum);
    k_scan2<<<1, 256, 0, stream>>>(B_bsum, B_boff);
    k_scan3<<<NB, 256, 0, stream>>>(B_cnt, B_boff, B_off);

    k_v<<<1, 128, 0, stream>>>(We0, ae0, B_v);
    k_wepbf<<<1, 128, 0, stream>>>(epW, B_wepbf);
    k_alpha_mfma<<<N_EDGES / 256, 256, 0, stream>>>(eattr, B_wepbf, epb, B_v,
                                                    ei, B_off, B_cur, B_rec, B_easum_part);
    k_aloop<<<1, 128, 0, stream>>>(B_easum_part, B_v, B_aloop);
    k_fill_loop<<<NB, 256, 0, stream>>>(B_off, B_cur, B_aloop, B_rec);

    k_w2bf<<<32, 256, 0, stream>>>(W2, B_w2bf);
    k_wbf<<<8, 256, 0, stream>>>(W0, B_w0bf);
    k_wbf<<<8, 256, 0, stream>>>(W1, B_w1bf);
    k_wbf<<<8, 256, 0, stream>>>(W_out, B_woutbf);
    k_u<<<2, 256, 0, stream>>>(W2, as2, ad2, B_us, B_ud);
    k_proj_in<<<N_NODES / 4, 128, 0, stream>>>(x, W_in, b_in, B_h, B_h16);

    const int PB = (N_NODES + 63) / 64;
    // layer 0 (agg fused with residual+LN; also emits csrc from rec)
    k_proj_attn_mfma<<<PB, 256, 0, stream>>>(B_h16, B_w0bf, as0, ad0, B_hp16, B_ls, B_ld);
    k_agg32<true><<<N_NODES / 4, 256, 0, stream>>>(B_off, (const int4*)B_rec, B_csrc,
                                                   B_hp16, B_ls, B_ld,
                                                   bias0, g0, be0, B_h, B_h16,
                                                   nullptr, nullptr, nullptr, nullptr);

    // layer 1 (agg + LN + fused layer-2 ls/ld)
    k_proj_attn_mfma<<<PB, 256, 0, stream>>>(B_h16, B_w1bf, as1, ad1, B_hp16, B_ls, B_ld);
    k_agg32<false><<<N_NODES / 4, 256, 0, stream>>>(B_off, nullptr, B_csrc, B_hp16, B_ls, B_ld,
                                                    bias1, g1, be1, B_h, B_h16,
                                                    B_us, B_ud, B_ls2, B_ld2);

    // layer 2: aggregate inputs, then fused {W2-proj + LN + W_out-proj} via MFMA
    k_agg2<<<N_NODES / 4, 256, 0, stream>>>(B_off, B_csrc, B_h16, B_ls2, B_ld2, B_aggq);
    k_gemm_post<<<(N_NODES + 63) / 64, 256, 0, stream>>>(B_aggq, B_w2bf, bias2, g2, be2,
                                                         B_h, B_woutbf, b_out, out);
}

// Round 15
// 523.377 us; speedup vs baseline: 1.1794x; 1.0312x over previous
//
#include <hip/hip_runtime.h>
#include <hip/hip_bf16.h>
#include <math.h>

#define N_NODES 50000
#define N_EDGES 1600000
#define N_TOT   (N_EDGES + N_NODES)
#define NBKT 64

typedef unsigned short ushort_t;
typedef short short8v __attribute__((ext_vector_type(8)));
typedef float f32x4 __attribute__((ext_vector_type(4)));
typedef float f32x4v __attribute__((ext_vector_type(4)));
typedef int   i32x4v __attribute__((ext_vector_type(4)));

__device__ __forceinline__ float lrelu(float x) { return x > 0.f ? x : 0.2f * x; }
__device__ __forceinline__ float bf2f(ushort_t u) { return __uint_as_float((unsigned)u << 16); }
__device__ __forceinline__ ushort_t f2bf(float f) {
    union { __hip_bfloat16 b; ushort_t u; } cv;
    cv.b = __float2bfloat16(f);
    return cv.u;
}

// ---------------- CSR build ----------------
__global__ void k_count(const int* __restrict__ ei, int* __restrict__ cnt) {
    int e = blockIdx.x * 256 + threadIdx.x;
    if (e >= N_TOT) return;
    int dst = (e < N_EDGES) ? ei[N_EDGES + e] : (e - N_EDGES);
    atomicAdd(&cnt[dst], 1);
}

__global__ void k_scan1(const int* __restrict__ cnt, int* __restrict__ bsum) {
    __shared__ int ws[4];
    int g = blockIdx.x * 256 + threadIdx.x;
    int lane = threadIdx.x & 63, wv = threadIdx.x >> 6;
    int x = (g < N_NODES) ? cnt[g] : 0;
#pragma unroll
    for (int s = 1; s < 64; s <<= 1) x += __shfl_xor(x, s, 64);
    if (lane == 0) ws[wv] = x;
    __syncthreads();
    if (threadIdx.x == 0) bsum[blockIdx.x] = ws[0] + ws[1] + ws[2] + ws[3];
}

__global__ void k_scan2(const int* __restrict__ bsum, int* __restrict__ boff) {
    __shared__ int ws[4];
    const int NB = (N_NODES + 255) / 256;
    int t = threadIdx.x, lane = t & 63, wv = t >> 6;
    int v = (t < NB) ? bsum[t] : 0;
    int x = v;
#pragma unroll
    for (int s = 1; s < 64; s <<= 1) { int tt = __shfl_up(x, s, 64); if (lane >= s) x += tt; }
    if (lane == 63) ws[wv] = x;
    __syncthreads();
    int add = 0;
#pragma unroll
    for (int w = 0; w < 4; ++w) add += (w < wv) ? ws[w] : 0;
    x += add;
    if (t < NB) boff[t] = x - v;   // exclusive
}

__global__ void k_scan3(const int* __restrict__ cnt, const int* __restrict__ boff,
                        int* __restrict__ off) {
    __shared__ int ws[4];
    int g = blockIdx.x * 256 + threadIdx.x;
    int lane = threadIdx.x & 63, wv = threadIdx.x >> 6;
    int v = (g < N_NODES) ? cnt[g] : 0;
    int x = v;
#pragma unroll
    for (int s = 1; s < 64; s <<= 1) { int tt = __shfl_up(x, s, 64); if (lane >= s) x += tt; }
    if (lane == 63) ws[wv] = x;
    __syncthreads();
    int add = 0;
#pragma unroll
    for (int w = 0; w < 4; ++w) add += (w < wv) ? ws[w] : 0;
    x += add;
    if (g < N_NODES) off[g + 1] = boff[blockIdx.x] + x;
    if (g == 0) off[0] = 0;
}

// self-loop records: {n, aloop packed}
__global__ void k_fill_loop(const int* __restrict__ off, int* __restrict__ cur,
                            const float* __restrict__ aloop, int* __restrict__ rec) {
    int n = blockIdx.x * 256 + threadIdx.x;
    if (n >= N_NODES) return;
    unsigned ax = (unsigned)f2bf(aloop[0]) | ((unsigned)f2bf(aloop[1]) << 16);
    unsigned ay = (unsigned)f2bf(aloop[2]) | ((unsigned)f2bf(aloop[3]) << 16);
    int pos = off[n] + atomicAdd(&cur[n], 1);
    i32x4v r = {n, (int)ax, (int)ay, 0};
    __builtin_nontemporal_store(r, (i32x4v*)(rec + (size_t)pos * 4));
}

// ---------------- edge attention precompute ----------------
__global__ void k_v(const float* __restrict__ We0, const float* __restrict__ ae0,
                    float* __restrict__ v) {
    int t = threadIdx.x;            // 0..127
    int h = t >> 5, k = t & 31;
    float s = 0.f;
    for (int c = 0; c < 32; ++c) s += We0[k * 128 + h * 32 + c] * ae0[h * 32 + c];
    v[h * 32 + k] = s;
}

// epW (32x32 row-major) -> bf16 MFMA fragments (used as A = epW^T tiles)
__global__ void k_wepbf(const float* __restrict__ epW, ushort_t* __restrict__ Bp) {
    int t = threadIdx.x;              // 0..127
    if (t >= 128) return;
    int lane = t & 63, ct = t >> 6;
    int j = ct * 16 + (lane & 15);
    int kbase = (lane >> 4) * 8;
    ushort_t o[8];
#pragma unroll
    for (int jj = 0; jj < 8; ++jj) o[jj] = f2bf(epW[(kbase + jj) * 32 + j]);
    ((uint4*)Bp)[t] = *(uint4*)o;
}

// MFMA edge-attention (transposed) + fused CSR scatter; nt loads/stores; bucketed easum.
__global__ void k_alpha_mfma(const float* __restrict__ eattr, const ushort_t* __restrict__ Aw,
                             const float* __restrict__ epb, const float* __restrict__ v,
                             const int* __restrict__ ei, const int* __restrict__ off,
                             int* __restrict__ cur, int* __restrict__ rec,
                             float* __restrict__ easum_part) {
    __shared__ float sums[4][32];
    int tid = threadIdx.x;
    int lane = tid & 63, wv = tid >> 6;
    int c = lane & 15, g = lane >> 4;   // c = edge column, g = channel group
    int e0base = blockIdx.x * 256 + wv * 64;

    // hoisted: CSR slot reservation
    int e = e0base + lane;
    int src = __builtin_nontemporal_load(&ei[e]);
    int dst = __builtin_nontemporal_load(&ei[N_EDGES + e]);
    int pos = off[dst] + atomicAdd(&cur[dst], 1);

    // hoisted: stage all eattr tiles (streaming, don't pollute L2)
    f32x4v F0[4], F1[4];
#pragma unroll
    for (int t = 0; t < 4; ++t) {
        const f32x4v* ap = (const f32x4v*)(eattr + (size_t)(e0base + t * 16 + c) * 32 + g * 8);
        F0[t] = __builtin_nontemporal_load(ap);
        F1[t] = __builtin_nontemporal_load(ap + 1);
    }

    short8v a0 = ((const short8v*)Aw)[lane];        // channels 0-15
    short8v a1 = ((const short8v*)Aw)[64 + lane];   // channels 16-31

    float eb0[4], eb1[4], vv0[4][4], vv1[4][4];
#pragma unroll
    for (int r = 0; r < 4; ++r) {
        eb0[r] = epb[g * 4 + r];
        eb1[r] = epb[16 + g * 4 + r];
#pragma unroll
        for (int h = 0; h < 4; ++h) {
            vv0[h][r] = v[h * 32 + g * 4 + r];
            vv1[h][r] = v[h * 32 + 16 + g * 4 + r];
        }
    }

    float se0[4] = {0.f, 0.f, 0.f, 0.f}, se1[4] = {0.f, 0.f, 0.f, 0.f};
    uint2 oo0, oo1, oo2, oo3;
#pragma unroll
    for (int t = 0; t < 4; ++t) {
        f32x4v f0 = F0[t], f1 = F1[t];
        ushort_t ai[8];
        ai[0] = f2bf(f0.x); ai[1] = f2bf(f0.y); ai[2] = f2bf(f0.z); ai[3] = f2bf(f0.w);
        ai[4] = f2bf(f1.x); ai[5] = f2bf(f1.y); ai[6] = f2bf(f1.z); ai[7] = f2bf(f1.w);
        short8v b = *(short8v*)ai;                  // B = eattr^T fragment
        f32x4 acc0 = (f32x4){0.f, 0.f, 0.f, 0.f};
        f32x4 acc1 = (f32x4){0.f, 0.f, 0.f, 0.f};
        acc0 = __builtin_amdgcn_mfma_f32_16x16x32_bf16(a0, b, acc0, 0, 0, 0);
        acc1 = __builtin_amdgcn_mfma_f32_16x16x32_bf16(a1, b, acc1, 0, 0, 0);
        float p0 = 0.f, p1 = 0.f, p2 = 0.f, p3 = 0.f;
#pragma unroll
        for (int r = 0; r < 4; ++r) {
            float u0 = fmaxf(acc0[r] + eb0[r], 0.f);
            float u1 = fmaxf(acc1[r] + eb1[r], 0.f);
            se0[r] += u0; se1[r] += u1;
            p0 += u0 * vv0[0][r] + u1 * vv1[0][r];
            p1 += u0 * vv0[1][r] + u1 * vv1[1][r];
            p2 += u0 * vv0[2][r] + u1 * vv1[2][r];
            p3 += u0 * vv0[3][r] + u1 * vv1[3][r];
        }
        p0 += __shfl_xor(p0, 16, 64); p0 += __shfl_xor(p0, 32, 64);
        p1 += __shfl_xor(p1, 16, 64); p1 += __shfl_xor(p1, 32, 64);
        p2 += __shfl_xor(p2, 16, 64); p2 += __shfl_xor(p2, 32, 64);
        p3 += __shfl_xor(p3, 16, 64); p3 += __shfl_xor(p3, 32, 64);
        uint2 o;
        o.x = (unsigned)f2bf(p0) | ((unsigned)f2bf(p1) << 16);
        o.y = (unsigned)f2bf(p2) | ((unsigned)f2bf(p3) << 16);
        if (t == 0) oo0 = o; else if (t == 1) oo1 = o; else if (t == 2) oo2 = o; else oo3 = o;
    }
    uint2 o = oo0;
    o.x = (g == 1) ? oo1.x : o.x; o.y = (g == 1) ? oo1.y : o.y;
    o.x = (g == 2) ? oo2.x : o.x; o.y = (g == 2) ? oo2.y : o.y;
    o.x = (g == 3) ? oo3.x : o.x; o.y = (g == 3) ? oo3.y : o.y;
    i32x4v rv = {src, (int)o.x, (int)o.y, 0};
    __builtin_nontemporal_store(rv, (i32x4v*)(rec + (size_t)pos * 4));

    // easum partials (64-way bucketed)
#pragma unroll
    for (int r = 0; r < 4; ++r) {
#pragma unroll
        for (int m = 1; m < 16; m <<= 1) {
            se0[r] += __shfl_xor(se0[r], m, 64);
            se1[r] += __shfl_xor(se1[r], m, 64);
        }
    }
    if (c == 0) {
#pragma unroll
        for (int r = 0; r < 4; ++r) {
            sums[wv][g * 4 + r] = se0[r];
            sums[wv][16 + g * 4 + r] = se1[r];
        }
    }
    __syncthreads();
    if (tid < 32) {
        atomicAdd(&easum_part[(blockIdx.x & (NBKT - 1)) * 32 + tid],
                  sums[0][tid] + sums[1][tid] + sums[2][tid] + sums[3][tid]);
    }
}

// reduce easum buckets, then aloop[h] = mean(ea) . v[h]
__global__ void k_aloop(const float* __restrict__ easum_part, const float* __restrict__ v,
                        float* __restrict__ aloop) {
    __shared__ float es[32];
    int t = threadIdx.x;
    if (t < 32) {
        float s = 0.f;
        for (int b = 0; b < NBKT; ++b) s += easum_part[b * 32 + t];
        es[t] = s;
    }
    __syncthreads();
    if (t < 4) {
        float s = 0.f;
        for (int c = 0; c < 32; ++c) s += (es[c] * (1.f / (float)N_EDGES)) * v[t * 32 + c];
        aloop[t] = s;
    }
}

// ---------------- weight conversion: 128x128 f32 -> MFMA B-fragment bf16 ----------------
__global__ void k_wbf(const float* __restrict__ W, ushort_t* __restrict__ Bp) {
    int t = blockIdx.x * 256 + threadIdx.x;   // 0..2047
    if (t >= 2048) return;
    int lane = t & 63;
    int ct = (t >> 6) & 7;
    int kb = t >> 9;
    int j = ct * 16 + (lane & 15);
    int kbase = kb * 32 + (lane >> 4) * 8;
    ushort_t o[8];
#pragma unroll
    for (int jj = 0; jj < 8; ++jj) o[jj] = f2bf(W[(kbase + jj) * 128 + j]);
    ((uint4*)Bp)[t] = *(uint4*)o;
}

// W2 (512x128 effective) -> B-fragments
__global__ void k_w2bf(const float* __restrict__ W2, ushort_t* __restrict__ Bp) {
    int t = blockIdx.x * 256 + threadIdx.x;   // 0..8191
    if (t >= 8192) return;
    int lane = t & 63;
    int ct = (t >> 6) & 7;
    int kb = t >> 9;
    int j = ct * 16 + (lane & 15);
    int kbase = kb * 32 + (lane >> 4) * 8;
    ushort_t o[8];
#pragma unroll
    for (int jj = 0; jj < 8; ++jj) {
        int kk = kbase + jj;
        int h = kk >> 7, kp = kk & 127;
        o[jj] = f2bf(W2[kp * 512 + h * 128 + j]);
    }
    ((uint4*)Bp)[t] = *(uint4*)o;
}

// ---------------- GEMMs ----------------
__global__ void k_proj_in(const float* __restrict__ x, const float* __restrict__ W,
                          const float* __restrict__ b, float* __restrict__ h,
                          ushort_t* __restrict__ h16) {
    int j = threadIdx.x;               // 0..127
    int n0 = blockIdx.x * 4;
    const float* x0 = x + (size_t)n0 * 64;
    float a0 = 0.f, a1 = 0.f, a2 = 0.f, a3 = 0.f;
    for (int k = 0; k < 64; ++k) {
        float w = W[k * 128 + j];
        a0 += x0[k] * w;
        a1 += x0[64 + k] * w;
        a2 += x0[128 + k] * w;
        a3 += x0[192 + k] * w;
    }
    float bb = b[j];
    a0 = fmaxf(a0 + bb, 0.f); a1 = fmaxf(a1 + bb, 0.f);
    a2 = fmaxf(a2 + bb, 0.f); a3 = fmaxf(a3 + bb, 0.f);
    h[(size_t)(n0 + 0) * 128 + j] = a0;
    h[(size_t)(n0 + 1) * 128 + j] = a1;
    h[(size_t)(n0 + 2) * 128 + j] = a2;
    h[(size_t)(n0 + 3) * 128 + j] = a3;
    h16[(size_t)(n0 + 0) * 128 + j] = f2bf(a0);
    h16[(size_t)(n0 + 1) * 128 + j] = f2bf(a1);
    h16[(size_t)(n0 + 2) * 128 + j] = f2bf(a2);
    h16[(size_t)(n0 + 3) * 128 + j] = f2bf(a3);
}

// MFMA projection: hp16 = bf16(h16 @ Wbf); fused ls/ld
__global__ void k_proj_attn_mfma(const ushort_t* __restrict__ h16, const ushort_t* __restrict__ Bp,
                                 const float* __restrict__ as_, const float* __restrict__ ad_,
                                 ushort_t* __restrict__ hp16, float* __restrict__ ls,
                                 float* __restrict__ ld) {
    int tid = threadIdx.x;
    int lane = tid & 63, wid = tid >> 6;
    int n0 = blockIdx.x * 64 + wid * 16;
    int arow = n0 + (lane & 15);
    int arc = arow < N_NODES ? arow : 0;
    int koff = (lane >> 4) * 8;
    const short8v* ap = (const short8v*)(h16 + (size_t)arc * 128 + koff);
    const short8v* bp = (const short8v*)Bp;

    f32x4 acc[8];
#pragma unroll
    for (int ct = 0; ct < 8; ++ct) acc[ct] = (f32x4){0.f, 0.f, 0.f, 0.f};
#pragma unroll
    for (int kb = 0; kb < 4; ++kb) {
        short8v a = ap[kb * 4];
#pragma unroll
        for (int ct = 0; ct < 8; ++ct) {
            short8v b = bp[(kb * 8 + ct) * 64 + lane];
            acc[ct] = __builtin_amdgcn_mfma_f32_16x16x32_bf16(a, b, acc[ct], 0, 0, 0);
        }
    }

    int q = lane >> 4, c = lane & 15;
#pragma unroll
    for (int reg = 0; reg < 4; ++reg) {
        int row = n0 + q * 4 + reg;
        if (row < N_NODES) {
#pragma unroll
            for (int ct = 0; ct < 8; ++ct)
                hp16[(size_t)row * 128 + ct * 16 + c] = f2bf(acc[ct][reg]);
        }
    }
#pragma unroll
    for (int h = 0; h < 4; ++h) {
        float alo = as_[h * 32 + c], ahi = as_[h * 32 + 16 + c];
        float dlo = ad_[h * 32 + c], dhi = ad_[h * 32 + 16 + c];
#pragma unroll
        for (int reg = 0; reg < 4; ++reg) {
            float s = acc[2 * h][reg] * alo + acc[2 * h + 1][reg] * ahi;
            float d = acc[2 * h][reg] * dlo + acc[2 * h + 1][reg] * dhi;
#pragma unroll
            for (int m = 1; m < 16; m <<= 1) {
                s += __shfl_xor(s, m, 64);
                d += __shfl_xor(d, m, 64);
            }
            int row = n0 + q * 4 + reg;
            if (c == 0 && row < N_NODES) {
                ls[row * 4 + h] = s;
                ld[row * 4 + h] = d;
            }
        }
    }
}

// u_s[h,k] = sum_c W2[k, h*128+c] * as2[h,c] (and u_d)
__global__ void k_u(const float* __restrict__ W2, const float* __restrict__ as2,
                    const float* __restrict__ ad2, float* __restrict__ us,
                    float* __restrict__ ud) {
    int t = blockIdx.x * 256 + threadIdx.x;
    if (t >= 512) return;
    int h = t >> 7, k = t & 127;
    float ss = 0.f, dd = 0.f;
    for (int c = 0; c < 128; ++c) {
        float w = W2[k * 512 + h * 128 + c];
        ss += w * as2[h * 128 + c];
        dd += w * ad2[h * 128 + c];
    }
    us[h * 128 + k] = ss;
    ud[h * 128 + k] = dd;
}

// ---- GAT aggregation + fused residual/LayerNorm (+ csrc emit / ls2,ld2), 4 nodes/block --
template <bool L0>
__global__ void k_agg32(const int* __restrict__ off, const int4* __restrict__ rec,
                        int* __restrict__ csrc,
                        const ushort_t* __restrict__ hp16, const float* __restrict__ ls,
                        const float* __restrict__ ld,
                        const float* __restrict__ bias, const float* __restrict__ g,
                        const float* __restrict__ be,
                        float* h, ushort_t* __restrict__ h16,
                        const float* __restrict__ us, const float* __restrict__ ud,
                        float* __restrict__ ls2, float* __restrict__ ld2) {
    __shared__ float swt[4][64][4];
    __shared__ int ssrc[4][64];
    int wv = threadIdx.x >> 6, lane = threadIdx.x & 63;
    int n = blockIdx.x * 4 + wv;
    int beg = off[n], deg = off[n + 1] - beg;
    float4 ldv = *(const float4*)(ld + n * 4);

    int hsel = lane >> 4;   // head of channels {2*lane, 2*lane+1}
    float acc0 = 0.f, acc1 = 0.f;
    float d0 = 0.f, d1 = 0.f, d2 = 0.f, d3 = 0.f;
    for (int base = 0; base < deg; base += 64) {
        int i = base + lane;
        float w0 = 0, w1 = 0, w2 = 0, w3 = 0;
        int s = 0;
        if (i < deg) {
            float a0 = 0, a1 = 0, a2 = 0, a3 = 0;
            if (L0) {
                int4 r = rec[beg + i];
                s = r.x;
                csrc[beg + i] = s;   // fused extract for layers 1/2
                a0 = bf2f((ushort_t)((unsigned)r.y & 0xffffu));
                a1 = bf2f((ushort_t)((unsigned)r.y >> 16));
                a2 = bf2f((ushort_t)((unsigned)r.z & 0xffffu));
                a3 = bf2f((ushort_t)((unsigned)r.z >> 16));
            } else {
                s = csrc[beg + i];
            }
            float4 lsv = *(const float4*)(ls + s * 4);
            w0 = __expf(lrelu(lsv.x + ldv.x + a0)); d0 += w0;
            w1 = __expf(lrelu(lsv.y + ldv.y + a1)); d1 += w1;
            w2 = __expf(lrelu(lsv.z + ldv.z + a2)); d2 += w2;
            w3 = __expf(lrelu(lsv.w + ldv.w + a3)); d3 += w3;
        }
        *(float4*)&swt[wv][lane][0] = make_float4(w0, w1, w2, w3);
        ssrc[wv][lane] = s;
        int cnt = min(64, deg - base);
        int jj = 0;
        for (; jj + 8 <= cnt; jj += 8) {
            float w[8]; int sidx[8]; ushort2 v[8];
#pragma unroll
            for (int u = 0; u < 8; ++u) {
                w[u] = swt[wv][jj + u][hsel];
                sidx[u] = ssrc[wv][jj + u];
            }
#pragma unroll
            for (int u = 0; u < 8; ++u)
                v[u] = ((const ushort2*)(hp16 + (size_t)sidx[u] * 128))[lane];
#pragma unroll
            for (int u = 0; u < 8; ++u) {
                acc0 += bf2f(v[u].x) * w[u];
                acc1 += bf2f(v[u].y) * w[u];
            }
        }
        for (; jj + 4 <= cnt; jj += 4) {
            float w[4]; int sidx[4]; ushort2 v[4];
#pragma unroll
            for (int u = 0; u < 4; ++u) {
                w[u] = swt[wv][jj + u][hsel];
                sidx[u] = ssrc[wv][jj + u];
            }
#pragma unroll
            for (int u = 0; u < 4; ++u)
                v[u] = ((const ushort2*)(hp16 + (size_t)sidx[u] * 128))[lane];
#pragma unroll
            for (int u = 0; u < 4; ++u) {
                acc0 += bf2f(v[u].x) * w[u];
                acc1 += bf2f(v[u].y) * w[u];
            }
        }
        for (; jj < cnt; ++jj) {
            float wA = swt[wv][jj][hsel];
            int sA = ssrc[wv][jj];
            ushort2 vA = ((const ushort2*)(hp16 + (size_t)sA * 128))[lane];
            acc0 += bf2f(vA.x) * wA;
            acc1 += bf2f(vA.y) * wA;
        }
    }
#pragma unroll
    for (int k = 1; k < 64; k <<= 1) {
        d0 += __shfl_xor(d0, k, 64); d1 += __shfl_xor(d1, k, 64);
        d2 += __shfl_xor(d2, k, 64); d3 += __shfl_xor(d3, k, 64);
    }
    float dsel = (hsel == 0) ? d0 : (hsel == 1) ? d1 : (hsel == 2) ? d2 : d3;
    float2 bb = ((const float2*)bias)[lane];
    size_t hbase = (size_t)n * 128;
    float2 hres = ((const float2*)(h + hbase))[lane];
    float v0 = acc0 / dsel + bb.x + hres.x;
    float v1 = acc1 / dsel + bb.y + hres.y;
    float s = v0 + v1, ss = v0 * v0 + v1 * v1;
#pragma unroll
    for (int k = 1; k < 64; k <<= 1) { s += __shfl_xor(s, k, 64); ss += __shfl_xor(ss, k, 64); }
    float mean = s * (1.f / 128.f);
    float var = ss * (1.f / 128.f) - mean * mean;
    float inv = rsqrtf(var + 1e-5f);
    float2 gg = ((const float2*)g)[lane];
    float2 bee = ((const float2*)be)[lane];
    float r0 = (v0 - mean) * inv * gg.x + bee.x;
    float r1 = (v1 - mean) * inv * gg.y + bee.y;
    ((float2*)(h + hbase))[lane] = make_float2(r0, r1);
    ushort2 o16; o16.x = f2bf(r0); o16.y = f2bf(r1);
    ((ushort2*)(h16 + hbase))[lane] = o16;

    if (!L0) {
        float sh[4], dh[4];
#pragma unroll
        for (int hh = 0; hh < 4; ++hh) {
            float2 u2 = ((const float2*)(us + hh * 128))[lane];
            float2 w2 = ((const float2*)(ud + hh * 128))[lane];
            sh[hh] = r0 * u2.x + r1 * u2.y;
            dh[hh] = r0 * w2.x + r1 * w2.y;
        }
#pragma unroll
        for (int k = 1; k < 64; k <<= 1) {
#pragma unroll
            for (int hh = 0; hh < 4; ++hh) {
                sh[hh] += __shfl_xor(sh[hh], k, 64);
                dh[hh] += __shfl_xor(dh[hh], k, 64);
            }
        }
        if (lane == 0) {
#pragma unroll
            for (int hh = 0; hh < 4; ++hh) {
                ls2[n * 4 + hh] = sh[hh];
                ld2[n * 4 + hh] = dh[hh];
            }
        }
    }
}

// ---------- layer-2 aggregation: single-pass, gather INPUT h (bf16), 4 nodes/block --
__global__ void k_agg2(const int* __restrict__ off, const int* __restrict__ csrc,
                       const ushort_t* __restrict__ h16, const float* __restrict__ ls,
                       const float* __restrict__ ld, ushort_t* __restrict__ aggq) {
    __shared__ float4 swt[4][64];
    __shared__ int ssrc[4][64];
    int wv = threadIdx.x >> 6, lane = threadIdx.x & 63;
    int n = blockIdx.x * 4 + wv;
    int beg = off[n], deg = off[n + 1] - beg;
    float4 ldv = *(const float4*)(ld + n * 4);

    float a00 = 0, a01 = 0, a10 = 0, a11 = 0, a20 = 0, a21 = 0, a30 = 0, a31 = 0;
    float d0 = 0, d1 = 0, d2 = 0, d3 = 0;
    for (int base = 0; base < deg; base += 64) {
        int i = base + lane;
        float w0 = 0, w1 = 0, w2 = 0, w3 = 0;
        int s = 0;
        if (i < deg) {
            s = csrc[beg + i];
            float4 lsv = *(const float4*)(ls + s * 4);
            w0 = __expf(lrelu(lsv.x + ldv.x)); d0 += w0;
            w1 = __expf(lrelu(lsv.y + ldv.y)); d1 += w1;
            w2 = __expf(lrelu(lsv.z + ldv.z)); d2 += w2;
            w3 = __expf(lrelu(lsv.w + ldv.w)); d3 += w3;
        }
        swt[wv][lane] = make_float4(w0, w1, w2, w3);
        ssrc[wv][lane] = s;
        int cnt = min(64, deg - base);
        int jj = 0;
        for (; jj + 4 <= cnt; jj += 4) {
            float4 w[4]; int sidx[4]; ushort2 v[4];
#pragma unroll
            for (int u = 0; u < 4; ++u) {
                w[u] = swt[wv][jj + u];
                sidx[u] = ssrc[wv][jj + u];
            }
#pragma unroll
            for (int u = 0; u < 4; ++u)
                v[u] = ((const ushort2*)(h16 + (size_t)sidx[u] * 128))[lane];
#pragma unroll
            for (int u = 0; u < 4; ++u) {
                float f0 = bf2f(v[u].x), f1 = bf2f(v[u].y);
                a00 += f0 * w[u].x; a01 += f1 * w[u].x;
                a10 += f0 * w[u].y; a11 += f1 * w[u].y;
                a20 += f0 * w[u].z; a21 += f1 * w[u].z;
                a30 += f0 * w[u].w; a31 += f1 * w[u].w;
            }
        }
        for (; jj < cnt; ++jj) {
            float4 w4 = swt[wv][jj];
            int sj = ssrc[wv][jj];
            ushort2 v = ((const ushort2*)(h16 + (size_t)sj * 128))[lane];
            float f0 = bf2f(v.x), f1 = bf2f(v.y);
            a00 += f0 * w4.x; a01 += f1 * w4.x;
            a10 += f0 * w4.y; a11 += f1 * w4.y;
            a20 += f0 * w4.z; a21 += f1 * w4.z;
            a30 += f0 * w4.w; a31 += f1 * w4.w;
        }
    }
#pragma unroll
    for (int k = 1; k < 64; k <<= 1) {
        d0 += __shfl_xor(d0, k, 64); d1 += __shfl_xor(d1, k, 64);
        d2 += __shfl_xor(d2, k, 64); d3 += __shfl_xor(d3, k, 64);
    }
    float r0 = 0.25f / d0, r1 = 0.25f / d1, r2 = 0.25f / d2, r3 = 0.25f / d3;
    ushort_t* base_p = aggq + (size_t)n * 512;
    ushort2 w;
    w.x = f2bf(a00 * r0); w.y = f2bf(a01 * r0); ((ushort2*)(base_p      ))[lane] = w;
    w.x = f2bf(a10 * r1); w.y = f2bf(a11 * r1); ((ushort2*)(base_p + 128))[lane] = w;
    w.x = f2bf(a20 * r2); w.y = f2bf(a21 * r2); ((ushort2*)(base_p + 256))[lane] = w;
    w.x = f2bf(a30 * r3); w.y = f2bf(a31 * r3); ((ushort2*)(base_p + 384))[lane] = w;
}

// --- MFMA GEMM: t = LN(aggq @ W2bf + bias2 + hbuf); out = t @ W_out + b_out (fused) ---
__global__ void k_gemm_post(const ushort_t* __restrict__ aggq, const ushort_t* __restrict__ Bp,
                            const float* __restrict__ bias, const float* __restrict__ g,
                            const float* __restrict__ be, const float* __restrict__ hbuf,
                            const ushort_t* __restrict__ Wout_bp, const float* __restrict__ b_out,
                            float* __restrict__ out) {
    __shared__ ushort_t tile[4][16][136];   // per-wave 16x128 bf16, padded
    int tid = threadIdx.x;
    int lane = tid & 63, wid = tid >> 6;
    int n0 = blockIdx.x * 64 + wid * 16;
    int arow = n0 + (lane & 15);
    int arc = arow < N_NODES ? arow : 0;
    int koff = (lane >> 4) * 8;

    const short8v* ap = (const short8v*)(aggq + (size_t)arc * 512 + koff);
    const short8v* bp = (const short8v*)Bp;

    f32x4 acc[8];
#pragma unroll
    for (int ct = 0; ct < 8; ++ct) acc[ct] = (f32x4){0.f, 0.f, 0.f, 0.f};
#pragma unroll
    for (int kb = 0; kb < 16; ++kb) {
        short8v a = ap[kb * 4];
#pragma unroll
        for (int ct = 0; ct < 8; ++ct) {
            short8v b = bp[(kb * 8 + ct) * 64 + lane];
            acc[ct] = __builtin_amdgcn_mfma_f32_16x16x32_bf16(a, b, acc[ct], 0, 0, 0);
        }
    }

    int q = lane >> 4, c = lane & 15;
    float gv[8], bev[8], bv[8];
#pragma unroll
    for (int ct = 0; ct < 8; ++ct) {
        int col = ct * 16 + c;
        gv[ct] = g[col]; bev[ct] = be[col]; bv[ct] = bias[col];
    }
#pragma unroll
    for (int reg = 0; reg < 4; ++reg) {
        int row = n0 + q * 4 + reg;
        int rc = row < N_NODES ? row : 0;
        float v[8];
        float s = 0.f, ss = 0.f;
#pragma unroll
        for (int ct = 0; ct < 8; ++ct) {
            float val = acc[ct][reg] + bv[ct] + hbuf[(size_t)rc * 128 + ct * 16 + c];
            v[ct] = val; s += val; ss += val * val;
        }
#pragma unroll
        for (int m = 1; m < 16; m <<= 1) {
            s += __shfl_xor(s, m, 64);
            ss += __shfl_xor(ss, m, 64);
        }
        float mean = s * (1.f / 128.f);
        float var = ss * (1.f / 128.f) - mean * mean;
        float inv = rsqrtf(var + 1e-5f);
        int lrow = q * 4 + reg;
#pragma unroll
        for (int ct = 0; ct < 8; ++ct)
            tile[wid][lrow][ct * 16 + c] = f2bf((v[ct] - mean) * inv * gv[ct] + bev[ct]);
    }

    const short8v* wp = (const short8v*)Wout_bp;
    f32x4 acc2[8];
#pragma unroll
    for (int ct = 0; ct < 8; ++ct) acc2[ct] = (f32x4){0.f, 0.f, 0.f, 0.f};
#pragma unroll
    for (int kb = 0; kb < 4; ++kb) {
        short8v a = *(const short8v*)&tile[wid][lane & 15][kb * 32 + koff];
#pragma unroll
        for (int ct = 0; ct < 8; ++ct) {
            short8v b = wp[(kb * 8 + ct) * 64 + lane];
            acc2[ct] = __builtin_amdgcn_mfma_f32_16x16x32_bf16(a, b, acc2[ct], 0, 0, 0);
        }
    }
    float bo[8];
#pragma unroll
    for (int ct = 0; ct < 8; ++ct) bo[ct] = b_out[ct * 16 + c];
#pragma unroll
    for (int reg = 0; reg < 4; ++reg) {
        int row = n0 + q * 4 + reg;
        if (row < N_NODES) {
#pragma unroll
            for (int ct = 0; ct < 8; ++ct)
                out[(size_t)row * 128 + ct * 16 + c] = acc2[ct][reg] + bo[ct];
        }
    }
}

extern "C" void kernel_launch(void* const* d_in, const int* in_sizes, int n_in,
                              void* d_out, int out_size, void* d_ws, size_t ws_size,
                              hipStream_t stream) {
    const float* x     = (const float*)d_in[0];
    const int*   ei    = (const int*)d_in[1];
    const float* eattr = (const float*)d_in[2];
    const float* W_in  = (const float*)d_in[3];
    const float* b_in  = (const float*)d_in[4];
    const float* epW   = (const float*)d_in[5];
    const float* epb   = (const float*)d_in[6];
    const float* W0    = (const float*)d_in[7];
    const float* as0   = (const float*)d_in[8];
    const float* ad0   = (const float*)d_in[9];
    const float* We0   = (const float*)d_in[10];
    const float* ae0   = (const float*)d_in[11];
    const float* bias0 = (const float*)d_in[12];
    const float* g0    = (const float*)d_in[13];
    const float* be0   = (const float*)d_in[14];
    const float* W1    = (const float*)d_in[15];
    const float* as1   = (const float*)d_in[16];
    const float* ad1   = (const float*)d_in[17];
    const float* bias1 = (const float*)d_in[18];
    const float* g1    = (const float*)d_in[19];
    const float* be1   = (const float*)d_in[20];
    const float* W2    = (const float*)d_in[21];
    const float* as2   = (const float*)d_in[22];
    const float* ad2   = (const float*)d_in[23];
    const float* bias2 = (const float*)d_in[24];
    const float* g2    = (const float*)d_in[25];
    const float* be2   = (const float*)d_in[26];
    const float* W_out = (const float*)d_in[27];
    const float* b_out = (const float*)d_in[28];
    float* out = (float*)d_out;

    char* wp = (char*)d_ws;
    auto alloc = [&](size_t bytes) {
        char* p = wp;
        wp += (bytes + 255) & ~(size_t)255;
        return p;
    };
    float*    B_h    = (float*)alloc((size_t)N_NODES * 128 * 4);
    ushort_t* B_hp16 = (ushort_t*)alloc((size_t)N_NODES * 128 * 2);
    ushort_t* B_h16  = (ushort_t*)alloc((size_t)N_NODES * 128 * 2);
    // union: rec (N_TOT*16B) dies before aggq (N*512*2B) is written
    char*     B_u    = (char*)alloc(52800000);
    int*      B_rec  = (int*)B_u;
    ushort_t* B_aggq = (ushort_t*)B_u;
    float* B_ls  = (float*)alloc((size_t)N_NODES * 4 * 4);
    float* B_ld  = (float*)alloc((size_t)N_NODES * 4 * 4);
    float* B_ls2 = (float*)alloc((size_t)N_NODES * 4 * 4);
    float* B_ld2 = (float*)alloc((size_t)N_NODES * 4 * 4);
    int*   B_off = (int*)alloc((size_t)(N_NODES + 1) * 4);
    int*   B_cnt = (int*)alloc((size_t)N_NODES * 4);
    int*   B_cur = (int*)alloc((size_t)N_NODES * 4);
    int*   B_csrc = (int*)alloc((size_t)N_TOT * 4);
    int*   B_bsum = (int*)alloc(256 * 4);
    int*   B_boff = (int*)alloc(256 * 4);
    float* B_v    = (float*)alloc(128 * 4);
    float* B_easum_part = (float*)alloc(NBKT * 32 * 4);
    float* B_aloop = (float*)alloc(4 * 4);
    float* B_us   = (float*)alloc(512 * 4);
    float* B_ud   = (float*)alloc(512 * 4);
    ushort_t* B_w2bf   = (ushort_t*)alloc(8192 * 16);
    ushort_t* B_w0bf   = (ushort_t*)alloc(2048 * 16);
    ushort_t* B_w1bf   = (ushort_t*)alloc(2048 * 16);
    ushort_t* B_woutbf = (ushort_t*)alloc(2048 * 16);
    ushort_t* B_wepbf  = (ushort_t*)alloc(128 * 16);

    hipMemsetAsync(B_cnt, 0, (size_t)N_NODES * 4, stream);
    hipMemsetAsync(B_cur, 0, (size_t)N_NODES * 4, stream);
    hipMemsetAsync(B_easum_part, 0, NBKT * 32 * 4, stream);

    const int NB = (N_NODES + 255) / 256;
    int eblocks = (N_TOT + 255) / 256;
    k_count<<<eblocks, 256, 0, stream>>>(ei, B_cnt);
    k_scan1<<<NB, 256, 0, stream>>>(B_cnt, B_bsum);
    k_scan2<<<1, 256, 0, stream>>>(B_bsum, B_boff);
    k_scan3<<<NB, 256, 0, stream>>>(B_cnt, B_boff, B_off);

    k_v<<<1, 128, 0, stream>>>(We0, ae0, B_v);
    k_wepbf<<<1, 128, 0, stream>>>(epW, B_wepbf);
    k_alpha_mfma<<<N_EDGES / 256, 256, 0, stream>>>(eattr, B_wepbf, epb, B_v,
                                                    ei, B_off, B_cur, B_rec, B_easum_part);
    k_aloop<<<1, 128, 0, stream>>>(B_easum_part, B_v, B_aloop);
    k_fill_loop<<<NB, 256, 0, stream>>>(B_off, B_cur, B_aloop, B_rec);

    k_w2bf<<<32, 256, 0, stream>>>(W2, B_w2bf);
    k_wbf<<<8, 256, 0, stream>>>(W0, B_w0bf);
    k_wbf<<<8, 256, 0, stream>>>(W1, B_w1bf);
    k_wbf<<<8, 256, 0, stream>>>(W_out, B_woutbf);
    k_u<<<2, 256, 0, stream>>>(W2, as2, ad2, B_us, B_ud);
    k_proj_in<<<N_NODES / 4, 128, 0, stream>>>(x, W_in, b_in, B_h, B_h16);

    const int PB = (N_NODES + 63) / 64;
    // layer 0 (agg fused with residual+LN; also emits csrc from rec)
    k_proj_attn_mfma<<<PB, 256, 0, stream>>>(B_h16, B_w0bf, as0, ad0, B_hp16, B_ls, B_ld);
    k_agg32<true><<<N_NODES / 4, 256, 0, stream>>>(B_off, (const int4*)B_rec, B_csrc,
                                                   B_hp16, B_ls, B_ld,
                                                   bias0, g0, be0, B_h, B_h16,
                                                   nullptr, nullptr, nullptr, nullptr);

    // layer 1 (agg + LN + fused layer-2 ls/ld)
    k_proj_attn_mfma<<<PB, 256, 0, stream>>>(B_h16, B_w1bf, as1, ad1, B_hp16, B_ls, B_ld);
    k_agg32<false><<<N_NODES / 4, 256, 0, stream>>>(B_off, nullptr, B_csrc, B_hp16, B_ls, B_ld,
                                                    bias1, g1, be1, B_h, B_h16,
                                                    B_us, B_ud, B_ls2, B_ld2);

    // layer 2: aggregate inputs, then fused {W2-proj + LN + W_out-proj} via MFMA
    k_agg2<<<N_NODES / 4, 256, 0, stream>>>(B_off, B_csrc, B_h16, B_ls2, B_ld2, B_aggq);
    k_gemm_post<<<(N_NODES + 63) / 64, 256, 0, stream>>>(B_aggq, B_w2bf, bias2, g2, be2,
                                                         B_h, B_woutbf, b_out, out);
}